// Round 12
// baseline (5761.177 us; speedup 1.0000x reference)
//
#include <hip/hip_runtime.h>
#include <hip/hip_cooperative_groups.h>

namespace cg = cooperative_groups;

#define T_STEPS 64
#define BATCH   128
#define HID     1024
#define H3      3072
#define EMBD    1024
#define SLEN    128
#define BH      (BATCH * HID)

typedef __attribute__((ext_vector_type(8))) short short8;
typedef __attribute__((ext_vector_type(4))) float f32x4;

__device__ __forceinline__ unsigned short f2bf(float x) {
    unsigned int u = __float_as_uint(x);
    unsigned int r = (u + 0x7fffu + ((u >> 16) & 1u)) >> 16;
    return (unsigned short)r;
}
__device__ __forceinline__ float bf2f(unsigned short h) {
    return __uint_as_float(((unsigned int)h) << 16);
}
__device__ __forceinline__ unsigned int pk(unsigned short a, unsigned short b) {
    return (unsigned int)a | ((unsigned int)b << 16);
}
__device__ __forceinline__ void cvt8(const float4& x, const float4& y,
                                     uint4& H, uint4& L) {
    unsigned short h0 = f2bf(x.x), h1 = f2bf(x.y), h2 = f2bf(x.z), h3 = f2bf(x.w);
    unsigned short h4 = f2bf(y.x), h5 = f2bf(y.y), h6 = f2bf(y.z), h7 = f2bf(y.w);
    unsigned short l0 = f2bf(x.x - bf2f(h0)), l1 = f2bf(x.y - bf2f(h1));
    unsigned short l2 = f2bf(x.z - bf2f(h2)), l3 = f2bf(x.w - bf2f(h3));
    unsigned short l4 = f2bf(y.x - bf2f(h4)), l5 = f2bf(y.y - bf2f(h5));
    unsigned short l6 = f2bf(y.z - bf2f(h6)), l7 = f2bf(y.w - bf2f(h7));
    H = make_uint4(pk(h0,h1), pk(h2,h3), pk(h4,h5), pk(h6,h7));
    L = make_uint4(pk(l0,l1), pk(l2,l3), pk(l4,l5), pk(l6,l7));
}
__device__ __forceinline__ float sigf(float x) {
    return 1.f / (1.f + __expf(-x));
}

#define MF(A, B, ACC) ACC = __builtin_amdgcn_mfma_f32_16x16x32_bf16(A, B, ACC, 0, 0, 0)
#define TRI(AH, AL, WH, WL, ACC)  MF(AH, WL, ACC); MF(AL, WH, ACC); MF(AH, WH, ACC);

// ============== plane-conversion kernels (run once per call) ==============
__global__ __launch_bounds__(256) void conv_planes_k(
    const float* __restrict__ src, short* __restrict__ hi, short* __restrict__ lo)
{
    const long i8 = (long)blockIdx.x * 256 + threadIdx.x;
    float4 x = ((const float4*)src)[i8 * 2];
    float4 y = ((const float4*)src)[i8 * 2 + 1];
    uint4 H, L; cvt8(x, y, H, L);
    ((uint4*)hi)[i8] = H; ((uint4*)lo)[i8] = L;
}

// wcat[n][k] = k<1024 ? w_ih1[n][k] : w_hh1[n][k-1024]  (3072 x 2048)
__global__ __launch_bounds__(256) void conv_cat_k(
    const float* __restrict__ wih1, const float* __restrict__ whh1,
    short* __restrict__ hi, short* __restrict__ lo)
{
    const long i8 = (long)blockIdx.x * 256 + threadIdx.x;
    const int k8 = (int)(i8 & 255);
    const long row = i8 >> 8;
    const int k = k8 * 8;
    const float* s = (k < 1024) ? (wih1 + row * 1024 + k) : (whh1 + row * 1024 + (k - 1024));
    float4 x = ((const float4*)s)[0];
    float4 y = ((const float4*)s)[1];
    uint4 H, L; cvt8(x, y, H, L);
    ((uint4*)hi)[i8] = H; ((uint4*)lo)[i8] = L;
}

__global__ __launch_bounds__(256) void conv_gather_k(
    const float* __restrict__ emb, const int* __restrict__ input,
    short* __restrict__ hi, short* __restrict__ lo)
{
    const long i8 = (long)blockIdx.x * 256 + threadIdx.x;
    const int c8 = (int)(i8 & 127);
    const long row = i8 >> 7;
    const float* s = emb + (size_t)input[row] * 1024 + c8 * 8;
    float4 x = ((const float4*)s)[0];
    float4 y = ((const float4*)s)[1];
    uint4 H, L; cvt8(x, y, H, L);
    ((uint4*)hi)[i8] = H; ((uint4*)lo)[i8] = L;
}

// ============== big batched GEMM: 128x128 block tile ==============
template<int MODE, bool CONCAT, bool WLO>
__global__ __launch_bounds__(256, 2) void gemm_big(
    const short* __restrict__ A1h, const short* __restrict__ A1l,
    const short* __restrict__ A2h, const short* __restrict__ A2l,
    const short* __restrict__ Wh,  const short* __restrict__ Wl,
    int K, int nn,
    const float* __restrict__ bias,
    float* __restrict__ outf, short* __restrict__ outh, short* __restrict__ outl,
    int ldo)
{
    extern __shared__ short sm[];
    short* Asm = sm;
    short* Wsm = sm + 16384;
    const int tid = threadIdx.x;
    const int wv = tid >> 6, l = tid & 63;
    const int mq = wv >> 1, nq = wv & 1;
    const int gl = l >> 4, r16 = l & 15;

    const int cpx = gridDim.x >> 3;
    const int id = blockIdx.x;
    const int swz = (id & 7) * cpx + (id >> 3);
    const int bm = swz / nn, bn = swz % nn;
    const long Rbase = (long)bm * 128;
    const int  Cbase = bn * 128;

    const int lda = CONCAT ? (K >> 1) : K;
    const int NC = K >> 5;
    const int NCh = NC >> 1;

    const short *aP1[4], *aP2[4], *wP[4];
    int slda[4];
    #pragma unroll
    for (int j = 0; j < 4; ++j) {
        const int s = tid + j * 256;
        const int pl = s >> 9, sp = s & 511;
        const int row = ((sp >> 6) << 4) | (sp & 15);
        const int kg = (sp >> 4) & 3;
        slda[j] = s * 8;
        const short* a1 = pl ? A1l : A1h;
        aP1[j] = a1 + (Rbase + row) * (long)lda + kg * 8;
        if (CONCAT) {
            const short* a2 = pl ? A2l : A2h;
            aP2[j] = a2 + (Rbase + row) * (long)lda + kg * 8;
        } else aP2[j] = aP1[j];
        const short* wp = pl ? Wl : Wh;
        wP[j] = wp + ((long)Cbase + row) * (long)K + kg * 8;
    }

    f32x4 acc[4][4];
    #pragma unroll
    for (int i = 0; i < 4; ++i)
        #pragma unroll
        for (int j = 0; j < 4; ++j) acc[i][j] = (f32x4)0.f;

    short8 rA[4], rW[4];
    auto LOADC = [&](int c) {
        const bool p1 = !CONCAT || (c < NCh);
        const long ko = p1 ? (long)c * 32 : (long)c * 32 - (K >> 1);
        #pragma unroll
        for (int j = 0; j < 4; ++j) {
            rA[j] = *(const short8*)((p1 ? aP1[j] : aP2[j]) + ko);
            rW[j] = *(const short8*)(wP[j] + (long)c * 32);
        }
    };
    auto STORE = [&](int c) {
        const int b = (c & 1) << 13;
        #pragma unroll
        for (int j = 0; j < 4; ++j) {
            *(short8*)(Asm + b + slda[j]) = rA[j];
            *(short8*)(Wsm + b + slda[j]) = rW[j];
        }
    };

    LOADC(0); STORE(0); LOADC(1);
    __syncthreads();

    for (int c = 0; c < NC; ++c) {
        const int b = (c & 1) << 13;
        short8 ah[4], al[4], wh[4], wl[4];
        #pragma unroll
        for (int f = 0; f < 4; ++f) {
            const short* ab = Asm + b + ((mq * 4 + f) * 64 + l) * 8;
            ah[f] = *(const short8*)ab;
            al[f] = *(const short8*)(ab + 4096);
            const short* wb = Wsm + b + ((nq * 4 + f) * 64 + l) * 8;
            wh[f] = *(const short8*)wb;
            if (!WLO) wl[f] = *(const short8*)(wb + 4096);
        }
        if (c + 1 < NC) STORE(c + 1);
        if (c + 2 < NC) LOADC(c + 2);
        #pragma unroll
        for (int mf = 0; mf < 4; ++mf)
            #pragma unroll
            for (int nf = 0; nf < 4; ++nf) {
                if constexpr (WLO) {
                    MF(al[mf], wh[nf], acc[mf][nf]);
                    MF(ah[mf], wh[nf], acc[mf][nf]);
                } else {
                    TRI(ah[mf], al[mf], wh[nf], wl[nf], acc[mf][nf]);
                }
            }
        __syncthreads();
    }

    #pragma unroll
    for (int mf = 0; mf < 4; ++mf) {
        #pragma unroll
        for (int reg = 0; reg < 4; ++reg) {
            const long R = Rbase + mq * 64 + mf * 16 + gl * 4 + reg;
            #pragma unroll
            for (int nf = 0; nf < 4; ++nf) {
                const int col = Cbase + nq * 64 + nf * 16 + r16;
                float v = acc[mf][nf][reg];
                if constexpr (MODE == 0) {
                    outf[R * (long)ldo + col] = v + bias[col];
                } else if constexpr (MODE == 1) {
                    const unsigned short hi = f2bf(v), lo = f2bf(v - bf2f(hi));
                    outh[R * (long)ldo + col] = (short)hi;
                    outl[R * (long)ldo + col] = (short)lo;
                } else {
                    outf[R * (long)ldo + col] = tanhf(v);
                }
            }
        }
    }
}

// ============== recurrence GEMM core — EXACT R6/R11 structure ==============
// MODE 2: layer-0 gate: K=1024, DUO (W-hi only). gi = i-side (f32, H3).
// MODE 3: layer-1 concat: K=2048; first half (w_ih1) TRI, second (w_hh1) DUO;
//         n-gate halves split (acc[2]/acc[3]).
template<int MODE>
__device__ __forceinline__ void gru_core(
    int bm, int bj,
    const short* __restrict__ A1h, const short* __restrict__ A1l,
    const short* __restrict__ A2h, const short* __restrict__ A2l,
    const short* __restrict__ Wh,  const short* __restrict__ Wl,
    const float* __restrict__ bias, const float* __restrict__ bias2,
    const float* __restrict__ gi, const float* __restrict__ hprev,
    float* __restrict__ outf, short* __restrict__ outh, short* __restrict__ outl)
{
    extern __shared__ short sm[];
    constexpr int P = 3;
    constexpr int K = (MODE == 2) ? 1024 : 2048;
    constexpr int NC = K >> 6;
    constexpr int NCh = NC >> 1;
    const int ABUF = 8192, WBUF = P * 2048;
    short* Asm = sm;
    short* Wsm = sm + 2 * ABUF;
    const int tid = threadIdx.x;
    const int wv = tid >> 6, l = tid & 63;
    const int gl = l >> 4, r16 = l & 15;

    const short *a1hP[2], *a1lP[2], *a2hP[2], *a2lP[2];
    int aLds[2];
    #pragma unroll
    for (int i = 0; i < 2; ++i) {
        const int s = tid + i * 256;
        const int row = ((s >> 6) & 3) * 16 + (s & 15);
        const int kg  = ((s >> 8) << 2) | ((s >> 4) & 3);
        const long r = (long)bm * 64 + row;
        a1hP[i] = A1h + r * HID + kg * 8;
        a1lP[i] = A1l + r * HID + kg * 8;
        if (MODE == 3) {
            a2hP[i] = A2h + r * HID + kg * 8;
            a2lP[i] = A2l + r * HID + kg * 8;
        } else { a2hP[i] = a1hP[i]; a2lP[i] = a1lP[i]; }
        aLds[i] = s * 8;
    }
    const bool doW = tid < P * 64;
    const short *whP[2], *wlP[2];
    int wLds[2] = {0, 0};
    if (doW) {
        #pragma unroll
        for (int i = 0; i < 2; ++i) {
            const int s = tid + i * P * 64;
            const int kcw = s / (P * 64);
            const int rem = s - kcw * (P * 64);
            const int p = rem >> 6, ll = rem & 63;
            const int jr = ll & 15, g = ll >> 4;
            const int kg = kcw * 4 + g;
            const long grow = (long)(p << 10) + bj * 16 + jr;
            whP[i] = Wh + grow * (long)K + kg * 8;
            wlP[i] = Wl + grow * (long)K + kg * 8;
            wLds[i] = s * 8;
        }
    }

    constexpr int NACC = (MODE == 3) ? 4 : 3;
    f32x4 acc[NACC];
    #pragma unroll
    for (int i = 0; i < NACC; ++i) acc[i] = (f32x4)0.f;

    auto wloNeed = [&](int c) -> bool { return (MODE == 3) && (c < NCh); };

    short8 rAh[2], rAl[2], rWh[2], rWl[2];
    auto LOADC = [&](int c) {
        const bool part1 = (MODE == 2) || (c < NCh);
        const long ko = part1 ? (long)c * 64 : (long)c * 64 - (K >> 1);
        #pragma unroll
        for (int i = 0; i < 2; ++i) {
            rAh[i] = *(const short8*)((part1 ? a1hP[i] : a2hP[i]) + ko);
            rAl[i] = *(const short8*)((part1 ? a1lP[i] : a2lP[i]) + ko);
        }
        if (doW) {
            const bool wl = wloNeed(c);
            #pragma unroll
            for (int i = 0; i < 2; ++i) {
                rWh[i] = *(const short8*)(whP[i] + (long)c * 64);
                if (wl) rWl[i] = *(const short8*)(wlP[i] + (long)c * 64);
            }
        }
    };
    auto STORE = [&](int c) {
        const int b = c & 1;
        #pragma unroll
        for (int i = 0; i < 2; ++i) {
            *(short8*)(Asm + b * ABUF + aLds[i]) = rAh[i];
            *(short8*)(Asm + b * ABUF + 4096 + aLds[i]) = rAl[i];
        }
        if (doW) {
            const bool wl = wloNeed(c);
            #pragma unroll
            for (int i = 0; i < 2; ++i) {
                *(short8*)(Wsm + b * WBUF + wLds[i]) = rWh[i];
                if (wl) *(short8*)(Wsm + b * WBUF + P * 1024 + wLds[i]) = rWl[i];
            }
        }
    };

    LOADC(0); STORE(0); LOADC(1);
    __syncthreads();

    for (int c = 0; c < NC; ++c) {
        const int b = c & 1;
        const bool wl = wloNeed(c);
        short8 fah[2], fal[2], fwh[2][P], fwl[2][P];
        #pragma unroll
        for (int kc = 0; kc < 2; ++kc) {
            const short* ab = Asm + b * ABUF + (kc * 256 + wv * 64 + l) * 8;
            fah[kc] = *(const short8*)ab;
            fal[kc] = *(const short8*)(ab + 4096);
            #pragma unroll
            for (int p = 0; p < P; ++p) {
                const short* wb = Wsm + b * WBUF + (kc * (P * 64) + p * 64 + l) * 8;
                fwh[kc][p] = *(const short8*)wb;
                if (wl) fwl[kc][p] = *(const short8*)(wb + P * 1024);
            }
        }
        if (c + 1 < NC) STORE(c + 1);
        if (c + 2 < NC) LOADC(c + 2);
        #pragma unroll
        for (int kc = 0; kc < 2; ++kc) {
            if constexpr (MODE == 3) {
                if (c < NCh) {
                    TRI(fah[kc], fal[kc], fwh[kc][0], fwl[kc][0], acc[0]);
                    TRI(fah[kc], fal[kc], fwh[kc][1], fwl[kc][1], acc[1]);
                    TRI(fah[kc], fal[kc], fwh[kc][2], fwl[kc][2], acc[2]);
                } else {
                    MF(fal[kc], fwh[kc][0], acc[0]); MF(fah[kc], fwh[kc][0], acc[0]);
                    MF(fal[kc], fwh[kc][1], acc[1]); MF(fah[kc], fwh[kc][1], acc[1]);
                    MF(fal[kc], fwh[kc][2], acc[3]); MF(fah[kc], fwh[kc][2], acc[3]);
                }
            } else {
                #pragma unroll
                for (int p = 0; p < P; ++p) {
                    MF(fal[kc], fwh[kc][p], acc[p]); MF(fah[kc], fwh[kc][p], acc[p]);
                }
            }
        }
        __syncthreads();
    }

    const int jc = bj * 16 + r16;
    #pragma unroll
    for (int reg = 0; reg < 4; ++reg) {
        const long R = (long)bm * 64 + wv * 16 + gl * 4 + reg;
        float h;
        if constexpr (MODE == 2) {
            const float* orow = gi + R * H3;
            const float rr = sigf(orow[jc] + acc[0][reg] + bias[jc]);
            const float zz = sigf(orow[HID + jc] + acc[1][reg] + bias[HID + jc]);
            const float nn = tanhf(orow[2 * HID + jc] + rr * (acc[2][reg] + bias[2 * HID + jc]));
            h = (1.f - zz) * nn + zz * hprev[R * HID + jc];
        } else {
            const float rr = sigf(acc[0][reg] + bias[jc] + bias2[jc]);
            const float zz = sigf(acc[1][reg] + bias[HID + jc] + bias2[HID + jc]);
            const float nn = tanhf(acc[2][reg] + bias[2 * HID + jc] +
                                   rr * (acc[3][reg] + bias2[2 * HID + jc]));
            h = (1.f - zz) * nn + zz * hprev[R * HID + jc];
        }
        outf[R * HID + jc] = h;
        const unsigned short hb = f2bf(h), lb = f2bf(h - bf2f(hb));
        outh[R * HID + jc] = (short)hb;
        outl[R * HID + jc] = (short)lb;
    }
}

struct StepP {
    const short* hih; const short* hil;
    const float* h_in; const float* gi0;
    const short* whh0h;
    const short* wcath; const short* wcatl;
    const float* b_hh0; const float* b_ih1; const float* b_hh1;
    float* h0f; float* h1f;
    short* h0ah; short* h0al; short* h1ah; short* h1al;
};

// shared step body for both launch modes
__device__ __forceinline__ void step_body(int t, int role, int bm, int bj,
                                          const StepP& P)
{
    if (role == 0) {
        if (t >= T_STEPS) return;
        const short* a1h = t ? P.h0ah + (size_t)(t - 1) * BH : P.hih;
        const short* a1l = t ? P.h0al + (size_t)(t - 1) * BH : P.hil;
        gru_core<2>(bm, bj, a1h, a1l, nullptr, nullptr,
                    P.whh0h, nullptr, P.b_hh0, nullptr,
                    P.gi0 + (size_t)t * BATCH * H3,
                    t ? P.h0f + (size_t)((t - 1) & 1) * BH : P.h_in,
                    P.h0f + (size_t)(t & 1) * BH,
                    P.h0ah + (size_t)t * BH, P.h0al + (size_t)t * BH);
    } else {
        if (t < 1) return;
        const int s = t - 1;
        const short* a2h = s ? P.h1ah + (size_t)(s - 1) * BH : P.hih + BH;
        const short* a2l = s ? P.h1al + (size_t)(s - 1) * BH : P.hil + BH;
        gru_core<3>(bm, bj,
                    P.h0ah + (size_t)s * BH, P.h0al + (size_t)s * BH, a2h, a2l,
                    P.wcath, P.wcatl, P.b_ih1, P.b_hh1,
                    nullptr,
                    s ? P.h1f + (size_t)((s - 1) & 1) * BH : P.h_in + BH,
                    P.h1f + (size_t)(s & 1) * BH,
                    P.h1ah + (size_t)s * BH, P.h1al + (size_t)s * BH);
    }
}

// fallback: one phase per launch (exact R11 behavior)
__global__ __launch_bounds__(256) void step_k(int t, StepP P)
{
    const int id = blockIdx.x;
    const int xcd = id & 7, sub = (id >> 3) & 7, top = id >> 6;
    step_body(t, top >> 1, top & 1, xcd * 8 + sub, P);
}

// persistent cooperative: all 65 phases in one launch, grid.sync between
__global__ __launch_bounds__(256, 1) void rec2_k(StepP P)
{
    const int id = blockIdx.x;
    const int xcd = id & 7, sub = (id >> 3) & 7, top = id >> 6;
    const int role = top >> 1, bm = top & 1;
    const int bj = xcd * 8 + sub;
    cg::grid_group grid = cg::this_grid();

    for (int t = 0; t <= T_STEPS; ++t) {
        step_body(t, role, bm, bj, P);
        if (t < T_STEPS) {
            __threadfence();
            grid.sync();
        }
    }
}

// ============== batched attention scores + softmax (per b) ==============
__global__ __launch_bounds__(256) void scores_k(
    const short* __restrict__ Qh, const short* __restrict__ Ql,
    const short* __restrict__ Hh, const short* __restrict__ Hl,
    float* __restrict__ Pall)
{
    extern __shared__ short sm[];
    short* Asm = sm;
    short* Wsm = sm + 8192;
    const int b = blockIdx.x, tid = threadIdx.x;
    const int wv = tid >> 6, l = tid & 63;
    const int gl = l >> 4, cc = l & 15;

    const int arow = ((tid >> 6) & 3) * 16 + (tid & 15);
    const int ag   = (tid >> 4) & 3;
    const short* qhp = Qh + ((long)arow * BATCH + b) * HID + ag * 8;
    const short* qlp = Ql + ((long)arow * BATCH + b) * HID + ag * 8;
    const int aLds = tid * 8;

    const short *whp[2], *wlp[2]; int wLds[2];
    #pragma unroll
    for (int i = 0; i < 2; ++i) {
        const int s = tid + i * 256;
        const int srow = ((s >> 6) & 7) * 16 + (s & 15);
        const int sg   = (s >> 4) & 3;
        whp[i] = Hh + ((long)srow * BATCH + b) * HID + sg * 8;
        wlp[i] = Hl + ((long)srow * BATCH + b) * HID + sg * 8;
        wLds[i] = s * 8;
    }

    f32x4 acc[8];
    #pragma unroll
    for (int i = 0; i < 8; ++i) acc[i] = (f32x4)0.f;

    short8 rAh, rAl, rWh[2], rWl[2];
    auto LOADC = [&](int c) {
        rAh = *(const short8*)(qhp + c * 32);
        rAl = *(const short8*)(qlp + c * 32);
        #pragma unroll
        for (int i = 0; i < 2; ++i) {
            rWh[i] = *(const short8*)(whp[i] + c * 32);
            rWl[i] = *(const short8*)(wlp[i] + c * 32);
        }
    };
    auto STORE = [&](int c) {
        const int bb = c & 1;
        *(short8*)(Asm + bb * 4096 + aLds) = rAh;
        *(short8*)(Asm + bb * 4096 + 2048 + aLds) = rAl;
        #pragma unroll
        for (int i = 0; i < 2; ++i) {
            *(short8*)(Wsm + bb * 8192 + wLds[i]) = rWh[i];
            *(short8*)(Wsm + bb * 8192 + 4096 + wLds[i]) = rWl[i];
        }
    };

    LOADC(0); STORE(0); LOADC(1);
    __syncthreads();
    for (int c = 0; c < 32; ++c) {
        const int bb = c & 1;
        const short* abp = Asm + bb * 4096 + (wv * 64 + l) * 8;
        short8 ah = *(const short8*)abp;
        short8 al = *(const short8*)(abp + 2048);
        if (c + 1 < 32) STORE(c + 1);
        if (c + 2 < 32) LOADC(c + 2);
        #pragma unroll
        for (int jt = 0; jt < 8; ++jt) {
            const short* wbp = Wsm + bb * 8192 + (jt * 64 + l) * 8;
            short8 wh = *(const short8*)wbp;
            short8 wl = *(const short8*)(wbp + 4096);
            TRI(ah, al, wh, wl, acc[jt]);
        }
        __syncthreads();
    }

    #pragma unroll
    for (int reg = 0; reg < 4; ++reg) {
        float m = acc[0][reg];
        #pragma unroll
        for (int jt = 1; jt < 8; ++jt) m = fmaxf(m, acc[jt][reg]);
        #pragma unroll
        for (int off = 1; off < 16; off <<= 1) m = fmaxf(m, __shfl_xor(m, off));
        float e[8], ssum = 0.f;
        #pragma unroll
        for (int jt = 0; jt < 8; ++jt) { e[jt] = __expf(acc[jt][reg] - m); ssum += e[jt]; }
        #pragma unroll
        for (int off = 1; off < 16; off <<= 1) ssum += __shfl_xor(ssum, off);
        const float inv = 1.f / ssum;
        const int t = wv * 16 + gl * 4 + reg;
        #pragma unroll
        for (int jt = 0; jt < 8; ++jt)
            Pall[((long)t * BATCH + b) * SLEN + jt * 16 + cc] = e[jt] * inv;
    }
}

__global__ __launch_bounds__(256) void ctx_k(
    const float* __restrict__ Pall, const float* __restrict__ H,
    short* __restrict__ Ch, short* __restrict__ Cl)
{
    __shared__ float Ps[T_STEPS * SLEN];
    const int b = blockIdx.x, ht = blockIdx.y, tid = threadIdx.x;
    for (int i = 0; i < 32; ++i) {
        const int idx = i * 256 + tid;
        const int t = idx >> 7, s = idx & 127;
        Ps[idx] = Pall[((long)t * BATCH + b) * SLEN + s];
    }
    __syncthreads();
    const int col = ht * 256 + tid;
    for (int tg = 0; tg < 4; ++tg) {
        float a[16];
        #pragma unroll
        for (int j = 0; j < 16; ++j) a[j] = 0.f;
        for (int s = 0; s < SLEN; ++s) {
            const float hv = H[((long)s * BATCH + b) * HID + col];
            #pragma unroll
            for (int j = 0; j < 16; ++j)
                a[j] = fmaf(Ps[(tg * 16 + j) * SLEN + s], hv, a[j]);
        }
        #pragma unroll
        for (int j = 0; j < 16; ++j) {
            const long row = (long)(tg * 16 + j) * BATCH + b;
            const unsigned short hi = f2bf(a[j]);
            const unsigned short lo = f2bf(a[j] - bf2f(hi));
            Ch[row * HID + col] = (short)hi;
            Cl[row * HID + col] = (short)lo;
        }
    }
}

// =========================== launch ===========================
extern "C" void kernel_launch(void* const* d_in, const int* in_sizes, int n_in,
                              void* d_out, int out_size, void* d_ws, size_t ws_size,
                              hipStream_t stream)
{
    const int*   input = (const int*)  d_in[0];
    const float* h_in  = (const float*)d_in[1];
    const float* Hbuf  = (const float*)d_in[2];
    const float* emb   = (const float*)d_in[3];
    const float* w_ih  = (const float*)d_in[4];
    const float* w_hh  = (const float*)d_in[5];
    const float* b_ih  = (const float*)d_in[6];
    const float* b_hh  = (const float*)d_in[7];
    const float* L1    = (const float*)d_in[8];
    const float* L2    = (const float*)d_in[9];

    float* out = (float*)d_out;

    char* basep = (char*)d_ws;
    size_t off = 0;
    auto alloc = [&](size_t bytes) -> char* {
        off = (off + 255) & ~(size_t)255;
        char* p = basep + off; off += bytes; return p;
    };
    short* wih0h = (short*)alloc(3072L*1024*2); short* wih0l = (short*)alloc(3072L*1024*2);
    short* whh0h = (short*)alloc(3072L*1024*2); short* whh0l = (short*)alloc(3072L*1024*2);
    short* wcath = (short*)alloc(3072L*2048*2); short* wcatl = (short*)alloc(3072L*2048*2);
    short* l1h   = (short*)alloc(1024L*1024*2); short* l1l   = (short*)alloc(1024L*1024*2);
    short* l2h   = (short*)alloc(1024L*2048*2); short* l2l   = (short*)alloc(1024L*2048*2);
    short* Hh    = (short*)alloc(16777216L*2);  short* Hl    = (short*)alloc(16777216L*2);
    short* hih   = (short*)alloc(262144L*2);    short* hil   = (short*)alloc(262144L*2);
    short* h0ah  = (short*)alloc(8388608L*2);   short* h0al  = (short*)alloc(8388608L*2);
    short* h1ah  = (short*)alloc(8388608L*2);   short* h1al  = (short*)alloc(8388608L*2);
    short* eqh   = (short*)alloc(8388608L*2);   short* eql   = (short*)alloc(8388608L*2);
    float* gi0   = (float*)alloc(25165824L*4);
    float* h0f   = (float*)alloc(524288L*4);
    float* h1f   = (float*)alloc(524288L*4);
    float* Pall  = (float*)alloc(1048576L*4);
    short* ctxh  = (short*)gi0;                 // gi0 dead after step loop
    short* ctxl  = ctxh + 8388608L;

    const dim3 blk(256);
    const size_t SMB = 32768 * sizeof(short);                      // 65536
    const size_t SM3 = (2 * 8192 + 2 * 3 * 2048) * sizeof(short);  // 57344

    // ---- phase 0: plane conversions ----
    conv_planes_k<<<1536, blk, 0, stream>>>(w_ih, wih0h, wih0l);
    conv_planes_k<<<1536, blk, 0, stream>>>(w_hh, whh0h, whh0l);
    conv_cat_k<<<3072, blk, 0, stream>>>(w_ih + (size_t)H3 * EMBD,
                                         w_hh + (size_t)H3 * HID, wcath, wcatl);
    conv_planes_k<<<512,  blk, 0, stream>>>(L1, l1h, l1l);
    conv_planes_k<<<1024, blk, 0, stream>>>(L2, l2h, l2l);
    conv_planes_k<<<8192, blk, 0, stream>>>(Hbuf, Hh, Hl);
    conv_planes_k<<<128,  blk, 0, stream>>>(h_in, hih, hil);
    conv_gather_k<<<4096, blk, 0, stream>>>(emb, input, eqh, eql);

    // gi0_all = E @ w_ih0^T + b_ih0   (8192 x 3072 x 1024), WLO
    gemm_big<0, false, true><<<dim3(1536), blk, SMB, stream>>>(
        eqh, eql, nullptr, nullptr, wih0h, wih0l, 1024, 24,
        b_ih, gi0, nullptr, nullptr, H3);

    // ---- recurrence: one cooperative launch (fallback: 65 launches) ----
    StepP sp;
    sp.hih = hih; sp.hil = hil; sp.h_in = h_in; sp.gi0 = gi0;
    sp.whh0h = whh0h; sp.wcath = wcath; sp.wcatl = wcatl;
    sp.b_hh0 = b_hh; sp.b_ih1 = b_ih + H3; sp.b_hh1 = b_hh + H3;
    sp.h0f = h0f; sp.h1f = h1f;
    sp.h0ah = h0ah; sp.h0al = h0al; sp.h1ah = h1ah; sp.h1al = h1al;

    void* kargs[] = { (void*)&sp };
    hipError_t ce = hipLaunchCooperativeKernel((void*)rec2_k, dim3(256), blk,
                                               kargs, (uint32_t)SM3, stream);
    if (ce != hipSuccess) {
        for (int t = 0; t <= T_STEPS; ++t)
            step_k<<<dim3(256), blk, SM3, stream>>>(t, sp);
    }

    // ---- batched attention + output ----
    gemm_big<1, false, false><<<dim3(512), blk, SMB, stream>>>(
        h1ah, h1al, nullptr, nullptr, l1h, l1l, 1024, 8,
        nullptr, nullptr, eqh, eql, HID);
    scores_k<<<dim3(BATCH), blk, 49152, stream>>>(eqh, eql, Hh, Hl, Pall);
    ctx_k<<<dim3(BATCH, 4), blk, 0, stream>>>(Pall, Hbuf, ctxh, ctxl);
    gemm_big<2, true, false><<<dim3(512), blk, SMB, stream>>>(
        ctxh, ctxl, h1ah, h1al, l2h, l2l, 2048, 8,
        nullptr, out, nullptr, nullptr, HID);

    hipMemcpyAsync(out + (long)T_STEPS * BH, h0f + BH, (size_t)BH * 4,
                   hipMemcpyDeviceToDevice, stream);
    hipMemcpyAsync(out + (long)T_STEPS * BH + BH, h1f + BH, (size_t)BH * 4,
                   hipMemcpyDeviceToDevice, stream);
}

// Round 13
// 2232.440 us; speedup vs baseline: 2.5807x; 2.5807x over previous
//
#include <hip/hip_runtime.h>

#define T_STEPS 64
#define BATCH   128
#define HID     1024
#define H3      3072
#define EMBD    1024
#define SLEN    128
#define BH      (BATCH * HID)

typedef __attribute__((ext_vector_type(8))) short short8;
typedef __attribute__((ext_vector_type(4))) float f32x4;

__device__ __forceinline__ unsigned short f2bf(float x) {
    unsigned int u = __float_as_uint(x);
    unsigned int r = (u + 0x7fffu + ((u >> 16) & 1u)) >> 16;
    return (unsigned short)r;
}
__device__ __forceinline__ float bf2f(unsigned short h) {
    return __uint_as_float(((unsigned int)h) << 16);
}
__device__ __forceinline__ unsigned int pk(unsigned short a, unsigned short b) {
    return (unsigned int)a | ((unsigned int)b << 16);
}
__device__ __forceinline__ void cvt8(const float4& x, const float4& y,
                                     uint4& H, uint4& L) {
    unsigned short h0 = f2bf(x.x), h1 = f2bf(x.y), h2 = f2bf(x.z), h3 = f2bf(x.w);
    unsigned short h4 = f2bf(y.x), h5 = f2bf(y.y), h6 = f2bf(y.z), h7 = f2bf(y.w);
    unsigned short l0 = f2bf(x.x - bf2f(h0)), l1 = f2bf(x.y - bf2f(h1));
    unsigned short l2 = f2bf(x.z - bf2f(h2)), l3 = f2bf(x.w - bf2f(h3));
    unsigned short l4 = f2bf(y.x - bf2f(h4)), l5 = f2bf(y.y - bf2f(h5));
    unsigned short l6 = f2bf(y.z - bf2f(h6)), l7 = f2bf(y.w - bf2f(h7));
    H = make_uint4(pk(h0,h1), pk(h2,h3), pk(h4,h5), pk(h6,h7));
    L = make_uint4(pk(l0,l1), pk(l2,l3), pk(l4,l5), pk(l6,l7));
}
__device__ __forceinline__ float sigf(float x) {
    return 1.f / (1.f + __expf(-x));
}

#define MF(A, B, ACC) ACC = __builtin_amdgcn_mfma_f32_16x16x32_bf16(A, B, ACC, 0, 0, 0)
#define TRI(AH, AL, WH, WL, ACC)  MF(AH, WL, ACC); MF(AL, WH, ACC); MF(AH, WH, ACC);

// ============== plane-conversion kernels (run once per call) ==============
__global__ __launch_bounds__(256) void conv_planes_k(
    const float* __restrict__ src, short* __restrict__ hi, short* __restrict__ lo)
{
    const long i8 = (long)blockIdx.x * 256 + threadIdx.x;
    float4 x = ((const float4*)src)[i8 * 2];
    float4 y = ((const float4*)src)[i8 * 2 + 1];
    uint4 H, L; cvt8(x, y, H, L);
    ((uint4*)hi)[i8] = H; ((uint4*)lo)[i8] = L;
}

// wcat[n][k] = k<1024 ? w_ih1[n][k] : w_hh1[n][k-1024]  (3072 x 2048)
__global__ __launch_bounds__(256) void conv_cat_k(
    const float* __restrict__ wih1, const float* __restrict__ whh1,
    short* __restrict__ hi, short* __restrict__ lo)
{
    const long i8 = (long)blockIdx.x * 256 + threadIdx.x;
    const int k8 = (int)(i8 & 255);
    const long row = i8 >> 8;
    const int k = k8 * 8;
    const float* s = (k < 1024) ? (wih1 + row * 1024 + k) : (whh1 + row * 1024 + (k - 1024));
    float4 x = ((const float4*)s)[0];
    float4 y = ((const float4*)s)[1];
    uint4 H, L; cvt8(x, y, H, L);
    ((uint4*)hi)[i8] = H; ((uint4*)lo)[i8] = L;
}

__global__ __launch_bounds__(256) void conv_gather_k(
    const float* __restrict__ emb, const int* __restrict__ input,
    short* __restrict__ hi, short* __restrict__ lo)
{
    const long i8 = (long)blockIdx.x * 256 + threadIdx.x;
    const int c8 = (int)(i8 & 127);
    const long row = i8 >> 7;
    const float* s = emb + (size_t)input[row] * 1024 + c8 * 8;
    float4 x = ((const float4*)s)[0];
    float4 y = ((const float4*)s)[1];
    uint4 H, L; cvt8(x, y, H, L);
    ((uint4*)hi)[i8] = H; ((uint4*)lo)[i8] = L;
}

// ============== big batched GEMM: 128x128 block tile ==============
template<int MODE, bool CONCAT, bool WLO>
__global__ __launch_bounds__(256, 2) void gemm_big(
    const short* __restrict__ A1h, const short* __restrict__ A1l,
    const short* __restrict__ A2h, const short* __restrict__ A2l,
    const short* __restrict__ Wh,  const short* __restrict__ Wl,
    int K, int nn,
    const float* __restrict__ bias,
    float* __restrict__ outf, short* __restrict__ outh, short* __restrict__ outl,
    int ldo)
{
    extern __shared__ short sm[];
    short* Asm = sm;
    short* Wsm = sm + 16384;
    const int tid = threadIdx.x;
    const int wv = tid >> 6, l = tid & 63;
    const int mq = wv >> 1, nq = wv & 1;
    const int gl = l >> 4, r16 = l & 15;

    const int cpx = gridDim.x >> 3;
    const int id = blockIdx.x;
    const int swz = (id & 7) * cpx + (id >> 3);
    const int bm = swz / nn, bn = swz % nn;
    const long Rbase = (long)bm * 128;
    const int  Cbase = bn * 128;

    const int lda = CONCAT ? (K >> 1) : K;
    const int NC = K >> 5;
    const int NCh = NC >> 1;

    const short *aP1[4], *aP2[4], *wP[4];
    int slda[4];
    #pragma unroll
    for (int j = 0; j < 4; ++j) {
        const int s = tid + j * 256;
        const int pl = s >> 9, sp = s & 511;
        const int row = ((sp >> 6) << 4) | (sp & 15);
        const int kg = (sp >> 4) & 3;
        slda[j] = s * 8;
        const short* a1 = pl ? A1l : A1h;
        aP1[j] = a1 + (Rbase + row) * (long)lda + kg * 8;
        if (CONCAT) {
            const short* a2 = pl ? A2l : A2h;
            aP2[j] = a2 + (Rbase + row) * (long)lda + kg * 8;
        } else aP2[j] = aP1[j];
        const short* wp = pl ? Wl : Wh;
        wP[j] = wp + ((long)Cbase + row) * (long)K + kg * 8;
    }

    f32x4 acc[4][4];
    #pragma unroll
    for (int i = 0; i < 4; ++i)
        #pragma unroll
        for (int j = 0; j < 4; ++j) acc[i][j] = (f32x4)0.f;

    short8 rA[4], rW[4];
    auto LOADC = [&](int c) {
        const bool p1 = !CONCAT || (c < NCh);
        const long ko = p1 ? (long)c * 32 : (long)c * 32 - (K >> 1);
        #pragma unroll
        for (int j = 0; j < 4; ++j) {
            rA[j] = *(const short8*)((p1 ? aP1[j] : aP2[j]) + ko);
            rW[j] = *(const short8*)(wP[j] + (long)c * 32);
        }
    };
    auto STORE = [&](int c) {
        const int b = (c & 1) << 13;
        #pragma unroll
        for (int j = 0; j < 4; ++j) {
            *(short8*)(Asm + b + slda[j]) = rA[j];
            *(short8*)(Wsm + b + slda[j]) = rW[j];
        }
    };

    LOADC(0); STORE(0); LOADC(1);
    __syncthreads();

    for (int c = 0; c < NC; ++c) {
        const int b = (c & 1) << 13;
        short8 ah[4], al[4], wh[4], wl[4];
        #pragma unroll
        for (int f = 0; f < 4; ++f) {
            const short* ab = Asm + b + ((mq * 4 + f) * 64 + l) * 8;
            ah[f] = *(const short8*)ab;
            al[f] = *(const short8*)(ab + 4096);
            const short* wb = Wsm + b + ((nq * 4 + f) * 64 + l) * 8;
            wh[f] = *(const short8*)wb;
            if (!WLO) wl[f] = *(const short8*)(wb + 4096);
        }
        if (c + 1 < NC) STORE(c + 1);
        if (c + 2 < NC) LOADC(c + 2);
        #pragma unroll
        for (int mf = 0; mf < 4; ++mf)
            #pragma unroll
            for (int nf = 0; nf < 4; ++nf) {
                if constexpr (WLO) {
                    MF(al[mf], wh[nf], acc[mf][nf]);
                    MF(ah[mf], wh[nf], acc[mf][nf]);
                } else {
                    TRI(ah[mf], al[mf], wh[nf], wl[nf], acc[mf][nf]);
                }
            }
        __syncthreads();
    }

    #pragma unroll
    for (int mf = 0; mf < 4; ++mf) {
        #pragma unroll
        for (int reg = 0; reg < 4; ++reg) {
            const long R = Rbase + mq * 64 + mf * 16 + gl * 4 + reg;
            #pragma unroll
            for (int nf = 0; nf < 4; ++nf) {
                const int col = Cbase + nq * 64 + nf * 16 + r16;
                float v = acc[mf][nf][reg];
                if constexpr (MODE == 0) {
                    outf[R * (long)ldo + col] = v + bias[col];
                } else if constexpr (MODE == 1) {
                    const unsigned short hi = f2bf(v), lo = f2bf(v - bf2f(hi));
                    outh[R * (long)ldo + col] = (short)hi;
                    outl[R * (long)ldo + col] = (short)lo;
                } else {
                    outf[R * (long)ldo + col] = tanhf(v);
                }
            }
        }
    }
}

// ============== recurrence GEMM core — R11 structure + 3-deep prefetch
// with NAMED register sets and fully-unrolled chunk loop (rule #20 safe).
// MODE 2: layer-0 gate: K=1024, DUO (W-hi only). gi = i-side (f32, H3).
// MODE 3: layer-1 concat: K=2048; first half (w_ih1) TRI, second (w_hh1) DUO;
//         n-gate halves split (acc[2]/acc[3]).
template<int MODE>
__device__ __forceinline__ void gru_core(
    int bm, int bj,
    const short* __restrict__ A1h, const short* __restrict__ A1l,
    const short* __restrict__ A2h, const short* __restrict__ A2l,
    const short* __restrict__ Wh,  const short* __restrict__ Wl,
    const float* __restrict__ bias, const float* __restrict__ bias2,
    const float* __restrict__ gi, const float* __restrict__ hprev,
    float* __restrict__ outf, short* __restrict__ outh, short* __restrict__ outl)
{
    extern __shared__ short sm[];
    constexpr int P = 3;
    constexpr int K = (MODE == 2) ? 1024 : 2048;
    constexpr int NC = K >> 6;
    constexpr int NCh = NC >> 1;
    const int ABUF = 8192, WBUF = P * 2048;
    short* Asm = sm;
    short* Wsm = sm + 2 * ABUF;
    const int tid = threadIdx.x;
    const int wv = tid >> 6, l = tid & 63;
    const int gl = l >> 4, r16 = l & 15;

    const short *a1hP[2], *a1lP[2], *a2hP[2], *a2lP[2];
    int aLds[2];
    #pragma unroll
    for (int i = 0; i < 2; ++i) {
        const int s = tid + i * 256;
        const int row = ((s >> 6) & 3) * 16 + (s & 15);
        const int kg  = ((s >> 8) << 2) | ((s >> 4) & 3);
        const long r = (long)bm * 64 + row;
        a1hP[i] = A1h + r * HID + kg * 8;
        a1lP[i] = A1l + r * HID + kg * 8;
        if (MODE == 3) {
            a2hP[i] = A2h + r * HID + kg * 8;
            a2lP[i] = A2l + r * HID + kg * 8;
        } else { a2hP[i] = a1hP[i]; a2lP[i] = a1lP[i]; }
        aLds[i] = s * 8;
    }
    const bool doW = tid < P * 64;
    const short *whP[2], *wlP[2];
    int wLds[2] = {0, 0};
    if (doW) {
        #pragma unroll
        for (int i = 0; i < 2; ++i) {
            const int s = tid + i * P * 64;
            const int kcw = s / (P * 64);
            const int rem = s - kcw * (P * 64);
            const int p = rem >> 6, ll = rem & 63;
            const int jr = ll & 15, g = ll >> 4;
            const int kg = kcw * 4 + g;
            const long grow = (long)(p << 10) + bj * 16 + jr;
            whP[i] = Wh + grow * (long)K + kg * 8;
            wlP[i] = Wl + grow * (long)K + kg * 8;
            wLds[i] = s * 8;
        }
    }

    constexpr int NACC = (MODE == 3) ? 4 : 3;
    f32x4 acc[NACC];
    #pragma unroll
    for (int i = 0; i < NACC; ++i) acc[i] = (f32x4)0.f;

    auto wloNeed = [&](int c) -> bool { return (MODE == 3) && (c < NCh); };

    // ---- two NAMED register staging sets (chunk k uses set k&1) ----
    short8 sAh0[2], sAl0[2], sWh0[2], sWl0[2];
    short8 sAh1[2], sAl1[2], sWh1[2], sWl1[2];

#define LOADC_(c, sAh, sAl, sWh, sWl) do {                                      \
    const bool part1_ = (MODE == 2) || ((c) < NCh);                             \
    const long ko_ = part1_ ? (long)(c) * 64 : (long)(c) * 64 - (K >> 1);       \
    for (int i_ = 0; i_ < 2; ++i_) {                                            \
        sAh[i_] = *(const short8*)((part1_ ? a1hP[i_] : a2hP[i_]) + ko_);       \
        sAl[i_] = *(const short8*)((part1_ ? a1lP[i_] : a2lP[i_]) + ko_);       \
    }                                                                           \
    if (doW) {                                                                  \
        const bool wl_ = wloNeed(c);                                            \
        for (int i_ = 0; i_ < 2; ++i_) {                                        \
            sWh[i_] = *(const short8*)(whP[i_] + (long)(c) * 64);               \
            if (wl_) sWl[i_] = *(const short8*)(wlP[i_] + (long)(c) * 64);      \
        }                                                                       \
    } } while (0)

#define STORE_(c, sAh, sAl, sWh, sWl) do {                                      \
    const int b_ = (c) & 1;                                                     \
    for (int i_ = 0; i_ < 2; ++i_) {                                            \
        *(short8*)(Asm + b_ * ABUF + aLds[i_]) = sAh[i_];                       \
        *(short8*)(Asm + b_ * ABUF + 4096 + aLds[i_]) = sAl[i_];                \
    }                                                                           \
    if (doW) {                                                                  \
        const bool wl_ = wloNeed(c);                                            \
        for (int i_ = 0; i_ < 2; ++i_) {                                        \
            *(short8*)(Wsm + b_ * WBUF + wLds[i_]) = sWh[i_];                   \
            if (wl_) *(short8*)(Wsm + b_ * WBUF + P * 1024 + wLds[i_]) = sWl[i_];\
        }                                                                       \
    } } while (0)

    LOADC_(0, sAh0, sAl0, sWh0, sWl0);
    STORE_(0, sAh0, sAl0, sWh0, sWl0);
    LOADC_(1, sAh1, sAl1, sWh1, sWl1);
    LOADC_(2, sAh0, sAl0, sWh0, sWl0);
    __syncthreads();

    #pragma unroll
    for (int c = 0; c < NC; ++c) {
        const int b = c & 1;
        const bool wl = wloNeed(c);
        short8 fah[2], fal[2], fwh[2][P], fwl[2][P];
        #pragma unroll
        for (int kc = 0; kc < 2; ++kc) {
            const short* ab = Asm + b * ABUF + (kc * 256 + wv * 64 + l) * 8;
            fah[kc] = *(const short8*)ab;
            fal[kc] = *(const short8*)(ab + 4096);
            #pragma unroll
            for (int p = 0; p < P; ++p) {
                const short* wb = Wsm + b * WBUF + (kc * (P * 64) + p * 64 + l) * 8;
                fwh[kc][p] = *(const short8*)wb;
                if (wl) fwl[kc][p] = *(const short8*)(wb + P * 1024);
            }
        }
        if (c + 1 < NC) {
            if (((c + 1) & 1) == 0) STORE_(c + 1, sAh0, sAl0, sWh0, sWl0);
            else                    STORE_(c + 1, sAh1, sAl1, sWh1, sWl1);
        }
        if (c + 3 < NC) {
            if (((c + 3) & 1) == 0) LOADC_(c + 3, sAh0, sAl0, sWh0, sWl0);
            else                    LOADC_(c + 3, sAh1, sAl1, sWh1, sWl1);
        }
        #pragma unroll
        for (int kc = 0; kc < 2; ++kc) {
            if constexpr (MODE == 3) {
                if (c < NCh) {
                    TRI(fah[kc], fal[kc], fwh[kc][0], fwl[kc][0], acc[0]);
                    TRI(fah[kc], fal[kc], fwh[kc][1], fwl[kc][1], acc[1]);
                    TRI(fah[kc], fal[kc], fwh[kc][2], fwl[kc][2], acc[2]);
                } else {
                    MF(fal[kc], fwh[kc][0], acc[0]); MF(fah[kc], fwh[kc][0], acc[0]);
                    MF(fal[kc], fwh[kc][1], acc[1]); MF(fah[kc], fwh[kc][1], acc[1]);
                    MF(fal[kc], fwh[kc][2], acc[3]); MF(fah[kc], fwh[kc][2], acc[3]);
                }
            } else {
                #pragma unroll
                for (int p = 0; p < P; ++p) {
                    MF(fal[kc], fwh[kc][p], acc[p]); MF(fah[kc], fwh[kc][p], acc[p]);
                }
            }
        }
        __syncthreads();
    }
#undef LOADC_
#undef STORE_

    const int jc = bj * 16 + r16;
    #pragma unroll
    for (int reg = 0; reg < 4; ++reg) {
        const long R = (long)bm * 64 + wv * 16 + gl * 4 + reg;
        float h;
        if constexpr (MODE == 2) {
            const float* orow = gi + R * H3;
            const float rr = sigf(orow[jc] + acc[0][reg] + bias[jc]);
            const float zz = sigf(orow[HID + jc] + acc[1][reg] + bias[HID + jc]);
            const float nn = tanhf(orow[2 * HID + jc] + rr * (acc[2][reg] + bias[2 * HID + jc]));
            h = (1.f - zz) * nn + zz * hprev[R * HID + jc];
        } else {
            const float rr = sigf(acc[0][reg] + bias[jc] + bias2[jc]);
            const float zz = sigf(acc[1][reg] + bias[HID + jc] + bias2[HID + jc]);
            const float nn = tanhf(acc[2][reg] + bias[2 * HID + jc] +
                                   rr * (acc[3][reg] + bias2[2 * HID + jc]));
            h = (1.f - zz) * nn + zz * hprev[R * HID + jc];
        }
        outf[R * HID + jc] = h;
        const unsigned short hb = f2bf(h), lb = f2bf(h - bf2f(hb));
        outh[R * HID + jc] = (short)hb;
        outl[R * HID + jc] = (short)lb;
    }
}

// ============== XCD-pinned pipelined step kernel ==============
struct StepP {
    const short* hih; const short* hil;
    const float* h_in; const float* gi0;
    const short* whh0h;
    const short* wcath; const short* wcatl;
    const float* b_hh0; const float* b_ih1; const float* b_hh1;
    float* h0f; float* h1f;
    short* h0ah; short* h0al; short* h1ah; short* h1al;
};

__global__ __launch_bounds__(256) void step_k(int t, StepP P)
{
    const int id = blockIdx.x;
    const int xcd = id & 7, sub = (id >> 3) & 7, top = id >> 6;
    const int role = top >> 1, bm = top & 1;
    const int bj = xcd * 8 + sub;

    if (role == 0) {
        if (t >= T_STEPS) return;
        const short* a1h = t ? P.h0ah + (size_t)(t - 1) * BH : P.hih;
        const short* a1l = t ? P.h0al + (size_t)(t - 1) * BH : P.hil;
        gru_core<2>(bm, bj, a1h, a1l, nullptr, nullptr,
                    P.whh0h, nullptr, P.b_hh0, nullptr,
                    P.gi0 + (size_t)t * BATCH * H3,
                    t ? P.h0f + (size_t)((t - 1) & 1) * BH : P.h_in,
                    P.h0f + (size_t)(t & 1) * BH,
                    P.h0ah + (size_t)t * BH, P.h0al + (size_t)t * BH);
    } else {
        if (t < 1) return;
        const int s = t - 1;
        const short* a2h = s ? P.h1ah + (size_t)(s - 1) * BH : P.hih + BH;
        const short* a2l = s ? P.h1al + (size_t)(s - 1) * BH : P.hil + BH;
        gru_core<3>(bm, bj,
                    P.h0ah + (size_t)s * BH, P.h0al + (size_t)s * BH, a2h, a2l,
                    P.wcath, P.wcatl, P.b_ih1, P.b_hh1,
                    nullptr,
                    s ? P.h1f + (size_t)((s - 1) & 1) * BH : P.h_in + BH,
                    P.h1f + (size_t)(s & 1) * BH,
                    P.h1ah + (size_t)s * BH, P.h1al + (size_t)s * BH);
    }
}

// ============== batched attention scores + softmax (per b) ==============
__global__ __launch_bounds__(256) void scores_k(
    const short* __restrict__ Qh, const short* __restrict__ Ql,
    const short* __restrict__ Hh, const short* __restrict__ Hl,
    float* __restrict__ Pall)
{
    extern __shared__ short sm[];
    short* Asm = sm;
    short* Wsm = sm + 8192;
    const int b = blockIdx.x, tid = threadIdx.x;
    const int wv = tid >> 6, l = tid & 63;
    const int gl = l >> 4, cc = l & 15;

    const int arow = ((tid >> 6) & 3) * 16 + (tid & 15);
    const int ag   = (tid >> 4) & 3;
    const short* qhp = Qh + ((long)arow * BATCH + b) * HID + ag * 8;
    const short* qlp = Ql + ((long)arow * BATCH + b) * HID + ag * 8;
    const int aLds = tid * 8;

    const short *whp[2], *wlp[2]; int wLds[2];
    #pragma unroll
    for (int i = 0; i < 2; ++i) {
        const int s = tid + i * 256;
        const int srow = ((s >> 6) & 7) * 16 + (s & 15);
        const int sg   = (s >> 4) & 3;
        whp[i] = Hh + ((long)srow * BATCH + b) * HID + sg * 8;
        wlp[i] = Hl + ((long)srow * BATCH + b) * HID + sg * 8;
        wLds[i] = s * 8;
    }

    f32x4 acc[8];
    #pragma unroll
    for (int i = 0; i < 8; ++i) acc[i] = (f32x4)0.f;

    short8 rAh, rAl, rWh[2], rWl[2];
    auto LOADC = [&](int c) {
        rAh = *(const short8*)(qhp + c * 32);
        rAl = *(const short8*)(qlp + c * 32);
        #pragma unroll
        for (int i = 0; i < 2; ++i) {
            rWh[i] = *(const short8*)(whp[i] + c * 32);
            rWl[i] = *(const short8*)(wlp[i] + c * 32);
        }
    };
    auto STORE = [&](int c) {
        const int bb = c & 1;
        *(short8*)(Asm + bb * 4096 + aLds) = rAh;
        *(short8*)(Asm + bb * 4096 + 2048 + aLds) = rAl;
        #pragma unroll
        for (int i = 0; i < 2; ++i) {
            *(short8*)(Wsm + bb * 8192 + wLds[i]) = rWh[i];
            *(short8*)(Wsm + bb * 8192 + 4096 + wLds[i]) = rWl[i];
        }
    };

    LOADC(0); STORE(0); LOADC(1);
    __syncthreads();
    for (int c = 0; c < 32; ++c) {
        const int bb = c & 1;
        const short* abp = Asm + bb * 4096 + (wv * 64 + l) * 8;
        short8 ah = *(const short8*)abp;
        short8 al = *(const short8*)(abp + 2048);
        if (c + 1 < 32) STORE(c + 1);
        if (c + 2 < 32) LOADC(c + 2);
        #pragma unroll
        for (int jt = 0; jt < 8; ++jt) {
            const short* wbp = Wsm + bb * 8192 + (jt * 64 + l) * 8;
            short8 wh = *(const short8*)wbp;
            short8 wl = *(const short8*)(wbp + 4096);
            TRI(ah, al, wh, wl, acc[jt]);
        }
        __syncthreads();
    }

    #pragma unroll
    for (int reg = 0; reg < 4; ++reg) {
        float m = acc[0][reg];
        #pragma unroll
        for (int jt = 1; jt < 8; ++jt) m = fmaxf(m, acc[jt][reg]);
        #pragma unroll
        for (int off = 1; off < 16; off <<= 1) m = fmaxf(m, __shfl_xor(m, off));
        float e[8], ssum = 0.f;
        #pragma unroll
        for (int jt = 0; jt < 8; ++jt) { e[jt] = __expf(acc[jt][reg] - m); ssum += e[jt]; }
        #pragma unroll
        for (int off = 1; off < 16; off <<= 1) ssum += __shfl_xor(ssum, off);
        const float inv = 1.f / ssum;
        const int t = wv * 16 + gl * 4 + reg;
        #pragma unroll
        for (int jt = 0; jt < 8; ++jt)
            Pall[((long)t * BATCH + b) * SLEN + jt * 16 + cc] = e[jt] * inv;
    }
}

__global__ __launch_bounds__(256) void ctx_k(
    const float* __restrict__ Pall, const float* __restrict__ H,
    short* __restrict__ Ch, short* __restrict__ Cl)
{
    __shared__ float Ps[T_STEPS * SLEN];
    const int b = blockIdx.x, ht = blockIdx.y, tid = threadIdx.x;
    for (int i = 0; i < 32; ++i) {
        const int idx = i * 256 + tid;
        const int t = idx >> 7, s = idx & 127;
        Ps[idx] = Pall[((long)t * BATCH + b) * SLEN + s];
    }
    __syncthreads();
    const int col = ht * 256 + tid;
    for (int tg = 0; tg < 4; ++tg) {
        float a[16];
        #pragma unroll
        for (int j = 0; j < 16; ++j) a[j] = 0.f;
        for (int s = 0; s < SLEN; ++s) {
            const float hv = H[((long)s * BATCH + b) * HID + col];
            #pragma unroll
            for (int j = 0; j < 16; ++j)
                a[j] = fmaf(Ps[(tg * 16 + j) * SLEN + s], hv, a[j]);
        }
        #pragma unroll
        for (int j = 0; j < 16; ++j) {
            const long row = (long)(tg * 16 + j) * BATCH + b;
            const unsigned short hi = f2bf(a[j]);
            const unsigned short lo = f2bf(a[j] - bf2f(hi));
            Ch[row * HID + col] = (short)hi;
            Cl[row * HID + col] = (short)lo;
        }
    }
}

// =========================== launch ===========================
extern "C" void kernel_launch(void* const* d_in, const int* in_sizes, int n_in,
                              void* d_out, int out_size, void* d_ws, size_t ws_size,
                              hipStream_t stream)
{
    const int*   input = (const int*)  d_in[0];
    const float* h_in  = (const float*)d_in[1];
    const float* Hbuf  = (const float*)d_in[2];
    const float* emb   = (const float*)d_in[3];
    const float* w_ih  = (const float*)d_in[4];
    const float* w_hh  = (const float*)d_in[5];
    const float* b_ih  = (const float*)d_in[6];
    const float* b_hh  = (const float*)d_in[7];
    const float* L1    = (const float*)d_in[8];
    const float* L2    = (const float*)d_in[9];

    float* out = (float*)d_out;

    char* basep = (char*)d_ws;
    size_t off = 0;
    auto alloc = [&](size_t bytes) -> char* {
        off = (off + 255) & ~(size_t)255;
        char* p = basep + off; off += bytes; return p;
    };
    short* wih0h = (short*)alloc(3072L*1024*2); short* wih0l = (short*)alloc(3072L*1024*2);
    short* whh0h = (short*)alloc(3072L*1024*2); short* whh0l = (short*)alloc(3072L*1024*2);
    short* wcath = (short*)alloc(3072L*2048*2); short* wcatl = (short*)alloc(3072L*2048*2);
    short* l1h   = (short*)alloc(1024L*1024*2); short* l1l   = (short*)alloc(1024L*1024*2);
    short* l2h   = (short*)alloc(1024L*2048*2); short* l2l   = (short*)alloc(1024L*2048*2);
    short* Hh    = (short*)alloc(16777216L*2);  short* Hl    = (short*)alloc(16777216L*2);
    short* hih   = (short*)alloc(262144L*2);    short* hil   = (short*)alloc(262144L*2);
    short* h0ah  = (short*)alloc(8388608L*2);   short* h0al  = (short*)alloc(8388608L*2);
    short* h1ah  = (short*)alloc(8388608L*2);   short* h1al  = (short*)alloc(8388608L*2);
    short* eqh   = (short*)alloc(8388608L*2);   short* eql   = (short*)alloc(8388608L*2);
    float* gi0   = (float*)alloc(25165824L*4);
    float* h0f   = (float*)alloc(524288L*4);
    float* h1f   = (float*)alloc(524288L*4);
    float* Pall  = (float*)alloc(1048576L*4);
    short* ctxh  = (short*)gi0;                 // gi0 dead after step loop
    short* ctxl  = ctxh + 8388608L;

    const dim3 blk(256);
    const size_t SMB = 32768 * sizeof(short);                      // 65536
    const size_t SM3 = (2 * 8192 + 2 * 3 * 2048) * sizeof(short);  // 57344

    // ---- phase 0: plane conversions ----
    conv_planes_k<<<1536, blk, 0, stream>>>(w_ih, wih0h, wih0l);
    conv_planes_k<<<1536, blk, 0, stream>>>(w_hh, whh0h, whh0l);
    conv_cat_k<<<3072, blk, 0, stream>>>(w_ih + (size_t)H3 * EMBD,
                                         w_hh + (size_t)H3 * HID, wcath, wcatl);
    conv_planes_k<<<512,  blk, 0, stream>>>(L1, l1h, l1l);
    conv_planes_k<<<1024, blk, 0, stream>>>(L2, l2h, l2l);
    conv_planes_k<<<8192, blk, 0, stream>>>(Hbuf, Hh, Hl);
    conv_planes_k<<<128,  blk, 0, stream>>>(h_in, hih, hil);
    conv_gather_k<<<4096, blk, 0, stream>>>(emb, input, eqh, eql);

    // gi0_all = E @ w_ih0^T + b_ih0   (8192 x 3072 x 1024), WLO
    gemm_big<0, false, true><<<dim3(1536), blk, SMB, stream>>>(
        eqh, eql, nullptr, nullptr, wih0h, wih0l, 1024, 24,
        b_ih, gi0, nullptr, nullptr, H3);

    // ---- pipelined recurrence: 65 XCD-pinned launches ----
    StepP sp;
    sp.hih = hih; sp.hil = hil; sp.h_in = h_in; sp.gi0 = gi0;
    sp.whh0h = whh0h; sp.wcath = wcath; sp.wcatl = wcatl;
    sp.b_hh0 = b_hh; sp.b_ih1 = b_ih + H3; sp.b_hh1 = b_hh + H3;
    sp.h0f = h0f; sp.h1f = h1f;
    sp.h0ah = h0ah; sp.h0al = h0al; sp.h1ah = h1ah; sp.h1al = h1al;
    for (int t = 0; t <= T_STEPS; ++t)
        step_k<<<dim3(256), blk, SM3, stream>>>(t, sp);

    // ---- batched attention + output ----
    gemm_big<1, false, false><<<dim3(512), blk, SMB, stream>>>(
        h1ah, h1al, nullptr, nullptr, l1h, l1l, 1024, 8,
        nullptr, nullptr, eqh, eql, HID);
    scores_k<<<dim3(BATCH), blk, 49152, stream>>>(eqh, eql, Hh, Hl, Pall);
    ctx_k<<<dim3(BATCH, 4), blk, 0, stream>>>(Pall, Hbuf, ctxh, ctxl);
    gemm_big<2, true, false><<<dim3(512), blk, SMB, stream>>>(
        ctxh, ctxl, h1ah, h1al, l2h, l2l, 2048, 8,
        nullptr, out, nullptr, nullptr, HID);

    hipMemcpyAsync(out + (long)T_STEPS * BH, h0f + BH, (size_t)BH * 4,
                   hipMemcpyDeviceToDevice, stream);
    hipMemcpyAsync(out + (long)T_STEPS * BH + BH, h1f + BH, (size_t)BH * 4,
                   hipMemcpyDeviceToDevice, stream);
}

// Round 14
// 2104.910 us; speedup vs baseline: 2.7370x; 1.0606x over previous
//
#include <hip/hip_runtime.h>

#define T_STEPS 64
#define BATCH   128
#define HID     1024
#define H3      3072
#define EMBD    1024
#define SLEN    128
#define BH      (BATCH * HID)

typedef __attribute__((ext_vector_type(8))) short short8;
typedef __attribute__((ext_vector_type(4))) float f32x4;

__device__ __forceinline__ unsigned short f2bf(float x) {
    unsigned int u = __float_as_uint(x);
    unsigned int r = (u + 0x7fffu + ((u >> 16) & 1u)) >> 16;
    return (unsigned short)r;
}
__device__ __forceinline__ float bf2f(unsigned short h) {
    return __uint_as_float(((unsigned int)h) << 16);
}
__device__ __forceinline__ unsigned int pk(unsigned short a, unsigned short b) {
    return (unsigned int)a | ((unsigned int)b << 16);
}
__device__ __forceinline__ void cvt8(const float4& x, const float4& y,
                                     uint4& H, uint4& L) {
    unsigned short h0 = f2bf(x.x), h1 = f2bf(x.y), h2 = f2bf(x.z), h3 = f2bf(x.w);
    unsigned short h4 = f2bf(y.x), h5 = f2bf(y.y), h6 = f2bf(y.z), h7 = f2bf(y.w);
    unsigned short l0 = f2bf(x.x - bf2f(h0)), l1 = f2bf(x.y - bf2f(h1));
    unsigned short l2 = f2bf(x.z - bf2f(h2)), l3 = f2bf(x.w - bf2f(h3));
    unsigned short l4 = f2bf(y.x - bf2f(h4)), l5 = f2bf(y.y - bf2f(h5));
    unsigned short l6 = f2bf(y.z - bf2f(h6)), l7 = f2bf(y.w - bf2f(h7));
    H = make_uint4(pk(h0,h1), pk(h2,h3), pk(h4,h5), pk(h6,h7));
    L = make_uint4(pk(l0,l1), pk(l2,l3), pk(l4,l5), pk(l6,l7));
}
__device__ __forceinline__ float sigf(float x) {
    return 1.f / (1.f + __expf(-x));
}

#define MF(A, B, ACC) ACC = __builtin_amdgcn_mfma_f32_16x16x32_bf16(A, B, ACC, 0, 0, 0)
#define TRI(AH, AL, WH, WL, ACC)  MF(AH, WL, ACC); MF(AL, WH, ACC); MF(AH, WH, ACC);

// ============== plane-conversion kernels (run once per call) ==============
__global__ __launch_bounds__(256) void conv_planes_k(
    const float* __restrict__ src, short* __restrict__ hi, short* __restrict__ lo)
{
    const long i8 = (long)blockIdx.x * 256 + threadIdx.x;
    float4 x = ((const float4*)src)[i8 * 2];
    float4 y = ((const float4*)src)[i8 * 2 + 1];
    uint4 H, L; cvt8(x, y, H, L);
    ((uint4*)hi)[i8] = H; ((uint4*)lo)[i8] = L;
}

__global__ __launch_bounds__(256) void conv_gather_k(
    const float* __restrict__ emb, const int* __restrict__ input,
    short* __restrict__ hi, short* __restrict__ lo)
{
    const long i8 = (long)blockIdx.x * 256 + threadIdx.x;
    const int c8 = (int)(i8 & 127);
    const long row = i8 >> 7;
    const float* s = emb + (size_t)input[row] * 1024 + c8 * 8;
    float4 x = ((const float4*)s)[0];
    float4 y = ((const float4*)s)[1];
    uint4 H, L; cvt8(x, y, H, L);
    ((uint4*)hi)[i8] = H; ((uint4*)lo)[i8] = L;
}

// ============== big batched GEMM: 128x128 block tile ==============
template<int MODE, bool CONCAT, bool WLO>
__global__ __launch_bounds__(256, 2) void gemm_big(
    const short* __restrict__ A1h, const short* __restrict__ A1l,
    const short* __restrict__ A2h, const short* __restrict__ A2l,
    const short* __restrict__ Wh,  const short* __restrict__ Wl,
    int K, int nn,
    const float* __restrict__ bias,
    float* __restrict__ outf, short* __restrict__ outh, short* __restrict__ outl,
    int ldo)
{
    extern __shared__ short sm[];
    short* Asm = sm;
    short* Wsm = sm + 16384;
    const int tid = threadIdx.x;
    const int wv = tid >> 6, l = tid & 63;
    const int mq = wv >> 1, nq = wv & 1;
    const int gl = l >> 4, r16 = l & 15;

    const int cpx = gridDim.x >> 3;
    const int id = blockIdx.x;
    const int swz = (id & 7) * cpx + (id >> 3);
    const int bm = swz / nn, bn = swz % nn;
    const long Rbase = (long)bm * 128;
    const int  Cbase = bn * 128;

    const int lda = CONCAT ? (K >> 1) : K;
    const int NC = K >> 5;
    const int NCh = NC >> 1;

    const short *aP1[4], *aP2[4], *wP[4];
    int slda[4];
    #pragma unroll
    for (int j = 0; j < 4; ++j) {
        const int s = tid + j * 256;
        const int pl = s >> 9, sp = s & 511;
        const int row = ((sp >> 6) << 4) | (sp & 15);
        const int kg = (sp >> 4) & 3;
        slda[j] = s * 8;
        const short* a1 = pl ? A1l : A1h;
        aP1[j] = a1 + (Rbase + row) * (long)lda + kg * 8;
        if (CONCAT) {
            const short* a2 = pl ? A2l : A2h;
            aP2[j] = a2 + (Rbase + row) * (long)lda + kg * 8;
        } else aP2[j] = aP1[j];
        const short* wp = pl ? Wl : Wh;
        wP[j] = wp + ((long)Cbase + row) * (long)K + kg * 8;
    }

    f32x4 acc[4][4];
    #pragma unroll
    for (int i = 0; i < 4; ++i)
        #pragma unroll
        for (int j = 0; j < 4; ++j) acc[i][j] = (f32x4)0.f;

    short8 rA[4], rW[4];
    auto LOADC = [&](int c) {
        const bool p1 = !CONCAT || (c < NCh);
        const long ko = p1 ? (long)c * 32 : (long)c * 32 - (K >> 1);
        #pragma unroll
        for (int j = 0; j < 4; ++j) {
            rA[j] = *(const short8*)((p1 ? aP1[j] : aP2[j]) + ko);
            rW[j] = *(const short8*)(wP[j] + (long)c * 32);
        }
    };
    auto STORE = [&](int c) {
        const int b = (c & 1) << 13;
        #pragma unroll
        for (int j = 0; j < 4; ++j) {
            *(short8*)(Asm + b + slda[j]) = rA[j];
            *(short8*)(Wsm + b + slda[j]) = rW[j];
        }
    };

    LOADC(0); STORE(0); LOADC(1);
    __syncthreads();

    for (int c = 0; c < NC; ++c) {
        const int b = (c & 1) << 13;
        short8 ah[4], al[4], wh[4], wl[4];
        #pragma unroll
        for (int f = 0; f < 4; ++f) {
            const short* ab = Asm + b + ((mq * 4 + f) * 64 + l) * 8;
            ah[f] = *(const short8*)ab;
            al[f] = *(const short8*)(ab + 4096);
            const short* wb = Wsm + b + ((nq * 4 + f) * 64 + l) * 8;
            wh[f] = *(const short8*)wb;
            if (!WLO) wl[f] = *(const short8*)(wb + 4096);
        }
        if (c + 1 < NC) STORE(c + 1);
        if (c + 2 < NC) LOADC(c + 2);
        #pragma unroll
        for (int mf = 0; mf < 4; ++mf)
            #pragma unroll
            for (int nf = 0; nf < 4; ++nf) {
                if constexpr (WLO) {
                    MF(al[mf], wh[nf], acc[mf][nf]);
                    MF(ah[mf], wh[nf], acc[mf][nf]);
                } else {
                    TRI(ah[mf], al[mf], wh[nf], wl[nf], acc[mf][nf]);
                }
            }
        __syncthreads();
    }

    #pragma unroll
    for (int mf = 0; mf < 4; ++mf) {
        #pragma unroll
        for (int reg = 0; reg < 4; ++reg) {
            const long R = Rbase + mq * 64 + mf * 16 + gl * 4 + reg;
            #pragma unroll
            for (int nf = 0; nf < 4; ++nf) {
                const int col = Cbase + nq * 64 + nf * 16 + r16;
                float v = acc[mf][nf][reg];
                if constexpr (MODE == 0) {
                    outf[R * (long)ldo + col] = v + bias[col];
                } else if constexpr (MODE == 1) {
                    const unsigned short hi = f2bf(v), lo = f2bf(v - bf2f(hi));
                    outh[R * (long)ldo + col] = (short)hi;
                    outl[R * (long)ldo + col] = (short)lo;
                } else {
                    outf[R * (long)ldo + col] = tanhf(v);
                }
            }
        }
    }
}

// ============== recurrence GEMM core — K=1024, R11 staging/prefetch ==============
// MODE 0: gi-GEMM: TRI (W hi+lo), outf[R*H3 + p*HID + jc] = acc + bias.
// MODE 2: gate: DUO (W hi only); gi = i-side f32 (stride H3); writes h f32
//         (stride HID) + bf16 hi/lo planes.
template<int MODE>
__device__ __forceinline__ void gru_core(
    int bm, int bj,
    const short* __restrict__ Ah, const short* __restrict__ Al,
    const short* __restrict__ Wh,  const short* __restrict__ Wl,
    const float* __restrict__ bias,
    const float* __restrict__ gi, const float* __restrict__ hprev,
    float* __restrict__ outf,
    short* __restrict__ outh, short* __restrict__ outl)
{
    extern __shared__ short sm[];
    constexpr int P = 3;
    constexpr int NC = 16;                 // K = 1024
    constexpr bool WL = (MODE == 0);       // need W lo plane (TRI)
    const int ABUF = 8192, WBUF = P * 2048;
    short* Asm = sm;
    short* Wsm = sm + 2 * ABUF;
    const int tid = threadIdx.x;
    const int wv = tid >> 6, l = tid & 63;
    const int gl = l >> 4, r16 = l & 15;

    const short *ahP[2], *alP[2];
    int aLds[2];
    #pragma unroll
    for (int i = 0; i < 2; ++i) {
        const int s = tid + i * 256;
        const int row = ((s >> 6) & 3) * 16 + (s & 15);
        const int kg  = ((s >> 8) << 2) | ((s >> 4) & 3);
        const long r = (long)bm * 64 + row;
        ahP[i] = Ah + r * HID + kg * 8;
        alP[i] = Al + r * HID + kg * 8;
        aLds[i] = s * 8;
    }
    const bool doW = tid < P * 64;
    const short *whP[2], *wlP[2];
    int wLds[2] = {0, 0};
    if (doW) {
        #pragma unroll
        for (int i = 0; i < 2; ++i) {
            const int s = tid + i * P * 64;
            const int kcw = s / (P * 64);
            const int rem = s - kcw * (P * 64);
            const int p = rem >> 6, ll = rem & 63;
            const int jr = ll & 15, g = ll >> 4;
            const int kg = kcw * 4 + g;
            const long grow = (long)(p << 10) + bj * 16 + jr;
            whP[i] = Wh + grow * (long)HID + kg * 8;
            wlP[i] = WL ? Wl + grow * (long)HID + kg * 8 : whP[i];
            wLds[i] = s * 8;
        }
    }

    f32x4 acc[P];
    #pragma unroll
    for (int i = 0; i < P; ++i) acc[i] = (f32x4)0.f;

    short8 rAh[2], rAl[2], rWh[2], rWl[2];
    auto LOADC = [&](int c) {
        const long ko = (long)c * 64;
        #pragma unroll
        for (int i = 0; i < 2; ++i) {
            rAh[i] = *(const short8*)(ahP[i] + ko);
            rAl[i] = *(const short8*)(alP[i] + ko);
        }
        if (doW) {
            #pragma unroll
            for (int i = 0; i < 2; ++i) {
                rWh[i] = *(const short8*)(whP[i] + ko);
                if (WL) rWl[i] = *(const short8*)(wlP[i] + ko);
            }
        }
    };
    auto STORE = [&](int c) {
        const int b = c & 1;
        #pragma unroll
        for (int i = 0; i < 2; ++i) {
            *(short8*)(Asm + b * ABUF + aLds[i]) = rAh[i];
            *(short8*)(Asm + b * ABUF + 4096 + aLds[i]) = rAl[i];
        }
        if (doW) {
            #pragma unroll
            for (int i = 0; i < 2; ++i) {
                *(short8*)(Wsm + b * WBUF + wLds[i]) = rWh[i];
                if (WL) *(short8*)(Wsm + b * WBUF + P * 1024 + wLds[i]) = rWl[i];
            }
        }
    };

    LOADC(0); STORE(0); LOADC(1);
    __syncthreads();

    for (int c = 0; c < NC; ++c) {
        const int b = c & 1;
        short8 fah[2], fal[2], fwh[2][P], fwl[2][P];
        #pragma unroll
        for (int kc = 0; kc < 2; ++kc) {
            const short* ab = Asm + b * ABUF + (kc * 256 + wv * 64 + l) * 8;
            fah[kc] = *(const short8*)ab;
            fal[kc] = *(const short8*)(ab + 4096);
            #pragma unroll
            for (int p = 0; p < P; ++p) {
                const short* wb = Wsm + b * WBUF + (kc * (P * 64) + p * 64 + l) * 8;
                fwh[kc][p] = *(const short8*)wb;
                if (WL) fwl[kc][p] = *(const short8*)(wb + P * 1024);
            }
        }
        if (c + 1 < NC) STORE(c + 1);
        if (c + 2 < NC) LOADC(c + 2);
        #pragma unroll
        for (int kc = 0; kc < 2; ++kc) {
            #pragma unroll
            for (int p = 0; p < P; ++p) {
                if constexpr (MODE == 0) {
                    TRI(fah[kc], fal[kc], fwh[kc][p], fwl[kc][p], acc[p]);
                } else {
                    MF(fal[kc], fwh[kc][p], acc[p]);
                    MF(fah[kc], fwh[kc][p], acc[p]);
                }
            }
        }
        __syncthreads();
    }

    const int jc = bj * 16 + r16;
    #pragma unroll
    for (int reg = 0; reg < 4; ++reg) {
        const long R = (long)bm * 64 + wv * 16 + gl * 4 + reg;
        if constexpr (MODE == 0) {
            #pragma unroll
            for (int p = 0; p < P; ++p)
                outf[R * H3 + p * HID + jc] = acc[p][reg] + bias[p * HID + jc];
        } else {
            const float* orow = gi + R * H3;
            const float rr = sigf(orow[jc] + acc[0][reg] + bias[jc]);
            const float zz = sigf(orow[HID + jc] + acc[1][reg] + bias[HID + jc]);
            const float nn = tanhf(orow[2 * HID + jc] + rr * (acc[2][reg] + bias[2 * HID + jc]));
            const float h = (1.f - zz) * nn + zz * hprev[R * HID + jc];
            outf[R * HID + jc] = h;
            const unsigned short hb = f2bf(h), lb = f2bf(h - bf2f(hb));
            outh[R * HID + jc] = (short)hb;
            outl[R * HID + jc] = (short)lb;
        }
    }
}

// ============== 3-role pipelined step kernel (384 blocks, XCD-pinned) ==============
// id -> xcd=id&7, sub=(id>>3)&7, top=id>>6 (0..5): role=top>>1, bm=top&1,
// bj=xcd*8+sub. Phase ph: role0 -> h0_ph ; role1 -> gi1_{ph-1} ; role2 -> h1_{ph-2}.
struct StepP {
    const short* hih; const short* hil;
    const float* h_in; const float* gi0; float* gi1;
    const short* whh0h;
    const short* wih1h; const short* wih1l; const short* whh1h;
    const float* b_hh0; const float* b_ih1; const float* b_hh1;
    float* h0f; float* h1f;
    short* h0ah; short* h0al; short* h1ah; short* h1al;
};

__global__ __launch_bounds__(256) void step_k(int ph, StepP P)
{
    const int id = blockIdx.x;
    const int xcd = id & 7, sub = (id >> 3) & 7, top = id >> 6;
    const int role = top >> 1, bm = top & 1;
    const int bj = xcd * 8 + sub;

    if (role == 0) {
        const int t = ph;
        if (t >= T_STEPS) return;
        const short* a1h = t ? P.h0ah + (size_t)(t - 1) * BH : P.hih;
        const short* a1l = t ? P.h0al + (size_t)(t - 1) * BH : P.hil;
        gru_core<2>(bm, bj, a1h, a1l, P.whh0h, nullptr, P.b_hh0,
                    P.gi0 + (size_t)t * BATCH * H3,
                    t ? P.h0f + (size_t)((t - 1) & 1) * BH : P.h_in,
                    P.h0f + (size_t)(t & 1) * BH,
                    P.h0ah + (size_t)t * BH, P.h0al + (size_t)t * BH);
    } else if (role == 1) {
        const int s = ph - 1;
        if (s < 0 || s >= T_STEPS) return;
        gru_core<0>(bm, bj,
                    P.h0ah + (size_t)s * BH, P.h0al + (size_t)s * BH,
                    P.wih1h, P.wih1l, P.b_ih1,
                    nullptr, nullptr,
                    P.gi1 + (size_t)(s & 1) * BATCH * H3,
                    nullptr, nullptr);
    } else {
        const int s = ph - 2;
        if (s < 0 || s >= T_STEPS) return;
        const short* a1h = s ? P.h1ah + (size_t)(s - 1) * BH : P.hih + BH;
        const short* a1l = s ? P.h1al + (size_t)(s - 1) * BH : P.hil + BH;
        gru_core<2>(bm, bj, a1h, a1l, P.whh1h, nullptr, P.b_hh1,
                    P.gi1 + (size_t)(s & 1) * BATCH * H3,
                    s ? P.h1f + (size_t)((s - 1) & 1) * BH : P.h_in + BH,
                    P.h1f + (size_t)(s & 1) * BH,
                    P.h1ah + (size_t)s * BH, P.h1al + (size_t)s * BH);
    }
}

// ============== batched attention scores + softmax (per b) ==============
__global__ __launch_bounds__(256) void scores_k(
    const short* __restrict__ Qh, const short* __restrict__ Ql,
    const short* __restrict__ Hh, const short* __restrict__ Hl,
    float* __restrict__ Pall)
{
    extern __shared__ short sm[];
    short* Asm = sm;
    short* Wsm = sm + 8192;
    const int b = blockIdx.x, tid = threadIdx.x;
    const int wv = tid >> 6, l = tid & 63;
    const int gl = l >> 4, cc = l & 15;

    const int arow = ((tid >> 6) & 3) * 16 + (tid & 15);
    const int ag   = (tid >> 4) & 3;
    const short* qhp = Qh + ((long)arow * BATCH + b) * HID + ag * 8;
    const short* qlp = Ql + ((long)arow * BATCH + b) * HID + ag * 8;
    const int aLds = tid * 8;

    const short *whp[2], *wlp[2]; int wLds[2];
    #pragma unroll
    for (int i = 0; i < 2; ++i) {
        const int s = tid + i * 256;
        const int srow = ((s >> 6) & 7) * 16 + (s & 15);
        const int sg   = (s >> 4) & 3;
        whp[i] = Hh + ((long)srow * BATCH + b) * HID + sg * 8;
        wlp[i] = Hl + ((long)srow * BATCH + b) * HID + sg * 8;
        wLds[i] = s * 8;
    }

    f32x4 acc[8];
    #pragma unroll
    for (int i = 0; i < 8; ++i) acc[i] = (f32x4)0.f;

    short8 rAh, rAl, rWh[2], rWl[2];
    auto LOADC = [&](int c) {
        rAh = *(const short8*)(qhp + c * 32);
        rAl = *(const short8*)(qlp + c * 32);
        #pragma unroll
        for (int i = 0; i < 2; ++i) {
            rWh[i] = *(const short8*)(whp[i] + c * 32);
            rWl[i] = *(const short8*)(wlp[i] + c * 32);
        }
    };
    auto STORE = [&](int c) {
        const int bb = c & 1;
        *(short8*)(Asm + bb * 4096 + aLds) = rAh;
        *(short8*)(Asm + bb * 4096 + 2048 + aLds) = rAl;
        #pragma unroll
        for (int i = 0; i < 2; ++i) {
            *(short8*)(Wsm + bb * 8192 + wLds[i]) = rWh[i];
            *(short8*)(Wsm + bb * 8192 + 4096 + wLds[i]) = rWl[i];
        }
    };

    LOADC(0); STORE(0); LOADC(1);
    __syncthreads();
    for (int c = 0; c < 32; ++c) {
        const int bb = c & 1;
        const short* abp = Asm + bb * 4096 + (wv * 64 + l) * 8;
        short8 ah = *(const short8*)abp;
        short8 al = *(const short8*)(abp + 2048);
        if (c + 1 < 32) STORE(c + 1);
        if (c + 2 < 32) LOADC(c + 2);
        #pragma unroll
        for (int jt = 0; jt < 8; ++jt) {
            const short* wbp = Wsm + bb * 8192 + (jt * 64 + l) * 8;
            short8 wh = *(const short8*)wbp;
            short8 wl = *(const short8*)(wbp + 4096);
            TRI(ah, al, wh, wl, acc[jt]);
        }
        __syncthreads();
    }

    #pragma unroll
    for (int reg = 0; reg < 4; ++reg) {
        float m = acc[0][reg];
        #pragma unroll
        for (int jt = 1; jt < 8; ++jt) m = fmaxf(m, acc[jt][reg]);
        #pragma unroll
        for (int off = 1; off < 16; off <<= 1) m = fmaxf(m, __shfl_xor(m, off));
        float e[8], ssum = 0.f;
        #pragma unroll
        for (int jt = 0; jt < 8; ++jt) { e[jt] = __expf(acc[jt][reg] - m); ssum += e[jt]; }
        #pragma unroll
        for (int off = 1; off < 16; off <<= 1) ssum += __shfl_xor(ssum, off);
        const float inv = 1.f / ssum;
        const int t = wv * 16 + gl * 4 + reg;
        #pragma unroll
        for (int jt = 0; jt < 8; ++jt)
            Pall[((long)t * BATCH + b) * SLEN + jt * 16 + cc] = e[jt] * inv;
    }
}

__global__ __launch_bounds__(256) void ctx_k(
    const float* __restrict__ Pall, const float* __restrict__ H,
    short* __restrict__ Ch, short* __restrict__ Cl)
{
    __shared__ float Ps[T_STEPS * SLEN];
    const int b = blockIdx.x, ht = blockIdx.y, tid = threadIdx.x;
    for (int i = 0; i < 32; ++i) {
        const int idx = i * 256 + tid;
        const int t = idx >> 7, s = idx & 127;
        Ps[idx] = Pall[((long)t * BATCH + b) * SLEN + s];
    }
    __syncthreads();
    const int col = ht * 256 + tid;
    for (int tg = 0; tg < 4; ++tg) {
        float a[16];
        #pragma unroll
        for (int j = 0; j < 16; ++j) a[j] = 0.f;
        for (int s = 0; s < SLEN; ++s) {
            const float hv = H[((long)s * BATCH + b) * HID + col];
            #pragma unroll
            for (int j = 0; j < 16; ++j)
                a[j] = fmaf(Ps[(tg * 16 + j) * SLEN + s], hv, a[j]);
        }
        #pragma unroll
        for (int j = 0; j < 16; ++j) {
            const long row = (long)(tg * 16 + j) * BATCH + b;
            const unsigned short hi = f2bf(a[j]);
            const unsigned short lo = f2bf(a[j] - bf2f(hi));
            Ch[row * HID + col] = (short)hi;
            Cl[row * HID + col] = (short)lo;
        }
    }
}

// =========================== launch ===========================
extern "C" void kernel_launch(void* const* d_in, const int* in_sizes, int n_in,
                              void* d_out, int out_size, void* d_ws, size_t ws_size,
                              hipStream_t stream)
{
    const int*   input = (const int*)  d_in[0];
    const float* h_in  = (const float*)d_in[1];
    const float* Hbuf  = (const float*)d_in[2];
    const float* emb   = (const float*)d_in[3];
    const float* w_ih  = (const float*)d_in[4];
    const float* w_hh  = (const float*)d_in[5];
    const float* b_ih  = (const float*)d_in[6];
    const float* b_hh  = (const float*)d_in[7];
    const float* L1    = (const float*)d_in[8];
    const float* L2    = (const float*)d_in[9];

    float* out = (float*)d_out;

    char* basep = (char*)d_ws;
    size_t off = 0;
    auto alloc = [&](size_t bytes) -> char* {
        off = (off + 255) & ~(size_t)255;
        char* p = basep + off; off += bytes; return p;
    };
    short* wih0h = (short*)alloc(3072L*1024*2); short* wih0l = (short*)alloc(3072L*1024*2);
    short* whh0h = (short*)alloc(3072L*1024*2); short* whh0l = (short*)alloc(3072L*1024*2);
    short* wih1h = (short*)alloc(3072L*1024*2); short* wih1l = (short*)alloc(3072L*1024*2);
    short* whh1h = (short*)alloc(3072L*1024*2); short* whh1l = (short*)alloc(3072L*1024*2);
    short* l1h   = (short*)alloc(1024L*1024*2); short* l1l   = (short*)alloc(1024L*1024*2);
    short* l2h   = (short*)alloc(1024L*2048*2); short* l2l   = (short*)alloc(1024L*2048*2);
    short* Hh    = (short*)alloc(16777216L*2);  short* Hl    = (short*)alloc(16777216L*2);
    short* hih   = (short*)alloc(262144L*2);    short* hil   = (short*)alloc(262144L*2);
    short* h0ah  = (short*)alloc(8388608L*2);   short* h0al  = (short*)alloc(8388608L*2);
    short* h1ah  = (short*)alloc(8388608L*2);   short* h1al  = (short*)alloc(8388608L*2);
    short* eqh   = (short*)alloc(8388608L*2);   short* eql   = (short*)alloc(8388608L*2);
    float* gi0   = (float*)alloc(25165824L*4);
    float* gi1   = (float*)alloc(2L*BATCH*H3*4);
    float* h0f   = (float*)alloc(524288L*4);
    float* h1f   = (float*)alloc(524288L*4);
    float* Pall  = (float*)alloc(1048576L*4);
    short* ctxh  = (short*)gi0;                 // gi0 dead after step loop
    short* ctxl  = ctxh + 8388608L;

    const dim3 blk(256);
    const size_t SMB = 32768 * sizeof(short);                      // 65536
    const size_t SM3 = (2 * 8192 + 2 * 3 * 2048) * sizeof(short);  // 57344

    // ---- phase 0: plane conversions ----
    conv_planes_k<<<1536, blk, 0, stream>>>(w_ih, wih0h, wih0l);
    conv_planes_k<<<1536, blk, 0, stream>>>(w_hh, whh0h, whh0l);
    conv_planes_k<<<1536, blk, 0, stream>>>(w_ih + 3145728L, wih1h, wih1l);
    conv_planes_k<<<1536, blk, 0, stream>>>(w_hh + 3145728L, whh1h, whh1l);
    conv_planes_k<<<512,  blk, 0, stream>>>(L1, l1h, l1l);
    conv_planes_k<<<1024, blk, 0, stream>>>(L2, l2h, l2l);
    conv_planes_k<<<8192, blk, 0, stream>>>(Hbuf, Hh, Hl);
    conv_planes_k<<<128,  blk, 0, stream>>>(h_in, hih, hil);
    conv_gather_k<<<4096, blk, 0, stream>>>(emb, input, eqh, eql);

    // gi0_all = E @ w_ih0^T + b_ih0   (8192 x 3072 x 1024), WLO
    gemm_big<0, false, true><<<dim3(1536), blk, SMB, stream>>>(
        eqh, eql, nullptr, nullptr, wih0h, wih0l, 1024, 24,
        b_ih, gi0, nullptr, nullptr, H3);

    // ---- 3-role pipelined recurrence: 66 XCD-pinned launches ----
    StepP sp;
    sp.hih = hih; sp.hil = hil; sp.h_in = h_in; sp.gi0 = gi0; sp.gi1 = gi1;
    sp.whh0h = whh0h;
    sp.wih1h = wih1h; sp.wih1l = wih1l; sp.whh1h = whh1h;
    sp.b_hh0 = b_hh; sp.b_ih1 = b_ih + H3; sp.b_hh1 = b_hh + H3;
    sp.h0f = h0f; sp.h1f = h1f;
    sp.h0ah = h0ah; sp.h0al = h0al; sp.h1ah = h1ah; sp.h1al = h1al;
    for (int ph = 0; ph <= T_STEPS + 1; ++ph)
        step_k<<<dim3(384), blk, SM3, stream>>>(ph, sp);

    // ---- batched attention + output ----
    gemm_big<1, false, false><<<dim3(512), blk, SMB, stream>>>(
        h1ah, h1al, nullptr, nullptr, l1h, l1l, 1024, 8,
        nullptr, nullptr, eqh, eql, HID);
    scores_k<<<dim3(BATCH), blk, 49152, stream>>>(eqh, eql, Hh, Hl, Pall);
    ctx_k<<<dim3(BATCH, 4), blk, 0, stream>>>(Pall, Hbuf, ctxh, ctxl);
    gemm_big<2, true, false><<<dim3(512), blk, SMB, stream>>>(
        ctxh, ctxl, h1ah, h1al, l2h, l2l, 2048, 8,
        nullptr, out, nullptr, nullptr, HID);

    hipMemcpyAsync(out + (long)T_STEPS * BH, h0f + BH, (size_t)BH * 4,
                   hipMemcpyDeviceToDevice, stream);
    hipMemcpyAsync(out + (long)T_STEPS * BH + BH, h1f + BH, (size_t)BH * 4,
                   hipMemcpyDeviceToDevice, stream);
}

// Round 15
// 2088.088 us; speedup vs baseline: 2.7591x; 1.0081x over previous
//
#include <hip/hip_runtime.h>

#define T_STEPS 64
#define BATCH   128
#define HID     1024
#define H3      3072
#define EMBD    1024
#define SLEN    128
#define BH      (BATCH * HID)

typedef __attribute__((ext_vector_type(8))) short short8;
typedef __attribute__((ext_vector_type(4))) float f32x4;

__device__ __forceinline__ unsigned short f2bf(float x) {
    unsigned int u = __float_as_uint(x);
    unsigned int r = (u + 0x7fffu + ((u >> 16) & 1u)) >> 16;
    return (unsigned short)r;
}
__device__ __forceinline__ float bf2f(unsigned short h) {
    return __uint_as_float(((unsigned int)h) << 16);
}
__device__ __forceinline__ unsigned int pk(unsigned short a, unsigned short b) {
    return (unsigned int)a | ((unsigned int)b << 16);
}
__device__ __forceinline__ void cvt8(const float4& x, const float4& y,
                                     uint4& H, uint4& L) {
    unsigned short h0 = f2bf(x.x), h1 = f2bf(x.y), h2 = f2bf(x.z), h3 = f2bf(x.w);
    unsigned short h4 = f2bf(y.x), h5 = f2bf(y.y), h6 = f2bf(y.z), h7 = f2bf(y.w);
    unsigned short l0 = f2bf(x.x - bf2f(h0)), l1 = f2bf(x.y - bf2f(h1));
    unsigned short l2 = f2bf(x.z - bf2f(h2)), l3 = f2bf(x.w - bf2f(h3));
    unsigned short l4 = f2bf(y.x - bf2f(h4)), l5 = f2bf(y.y - bf2f(h5));
    unsigned short l6 = f2bf(y.z - bf2f(h6)), l7 = f2bf(y.w - bf2f(h7));
    H = make_uint4(pk(h0,h1), pk(h2,h3), pk(h4,h5), pk(h6,h7));
    L = make_uint4(pk(l0,l1), pk(l2,l3), pk(l4,l5), pk(l6,l7));
}
__device__ __forceinline__ float sigf(float x) {
    return 1.f / (1.f + __expf(-x));
}

#define MF(A, B, ACC) ACC = __builtin_amdgcn_mfma_f32_16x16x32_bf16(A, B, ACC, 0, 0, 0)
#define TRI(AH, AL, WH, WL, ACC)  MF(AH, WL, ACC); MF(AL, WH, ACC); MF(AH, WH, ACC);

// ============== plane-conversion kernels (run once per call) ==============
template<bool LO>
__global__ __launch_bounds__(256) void conv_planes_k(
    const float* __restrict__ src, short* __restrict__ hi, short* __restrict__ lo)
{
    const long i8 = (long)blockIdx.x * 256 + threadIdx.x;
    float4 x = ((const float4*)src)[i8 * 2];
    float4 y = ((const float4*)src)[i8 * 2 + 1];
    uint4 H, L; cvt8(x, y, H, L);
    ((uint4*)hi)[i8] = H;
    if (LO) ((uint4*)lo)[i8] = L;
}

__global__ __launch_bounds__(256) void conv_gather_k(
    const float* __restrict__ emb, const int* __restrict__ input,
    short* __restrict__ hi, short* __restrict__ lo)
{
    const long i8 = (long)blockIdx.x * 256 + threadIdx.x;
    const int c8 = (int)(i8 & 127);
    const long row = i8 >> 7;
    const float* s = emb + (size_t)input[row] * 1024 + c8 * 8;
    float4 x = ((const float4*)s)[0];
    float4 y = ((const float4*)s)[1];
    uint4 H, L; cvt8(x, y, H, L);
    ((uint4*)hi)[i8] = H; ((uint4*)lo)[i8] = L;
}

// ============== big batched GEMM: 128x128 block tile ==============
// MODE 0: outf = acc + bias   MODE 1: plane store (+bias if given)
// MODE 2: outf = tanh(acc)    WLO: drop Ah*Wl term AND skip W-lo staging.
template<int MODE, bool CONCAT, bool WLO>
__global__ __launch_bounds__(256, 2) void gemm_big(
    const short* __restrict__ A1h, const short* __restrict__ A1l,
    const short* __restrict__ A2h, const short* __restrict__ A2l,
    const short* __restrict__ Wh,  const short* __restrict__ Wl,
    int K, int nn,
    const float* __restrict__ bias,
    float* __restrict__ outf, short* __restrict__ outh, short* __restrict__ outl,
    int ldo)
{
    extern __shared__ short sm[];
    short* Asm = sm;
    short* Wsm = sm + 16384;
    const int tid = threadIdx.x;
    const int wv = tid >> 6, l = tid & 63;
    const int mq = wv >> 1, nq = wv & 1;
    const int gl = l >> 4, r16 = l & 15;

    const int cpx = gridDim.x >> 3;
    const int id = blockIdx.x;
    const int swz = (id & 7) * cpx + (id >> 3);
    const int bm = swz / nn, bn = swz % nn;
    const long Rbase = (long)bm * 128;
    const int  Cbase = bn * 128;

    const int lda = CONCAT ? (K >> 1) : K;
    const int NC = K >> 5;
    const int NCh = NC >> 1;

    const short *aP1[4], *aP2[4], *wP[4];
    int slda[4];
    #pragma unroll
    for (int j = 0; j < 4; ++j) {
        const int s = tid + j * 256;
        const int pl = s >> 9, sp = s & 511;
        const int row = ((sp >> 6) << 4) | (sp & 15);
        const int kg = (sp >> 4) & 3;
        slda[j] = s * 8;
        const short* a1 = pl ? A1l : A1h;
        aP1[j] = a1 + (Rbase + row) * (long)lda + kg * 8;
        if (CONCAT) {
            const short* a2 = pl ? A2l : A2h;
            aP2[j] = a2 + (Rbase + row) * (long)lda + kg * 8;
        } else aP2[j] = aP1[j];
        const short* wp = pl ? Wl : Wh;
        wP[j] = wp + ((long)Cbase + row) * (long)K + kg * 8;
    }

    f32x4 acc[4][4];
    #pragma unroll
    for (int i = 0; i < 4; ++i)
        #pragma unroll
        for (int j = 0; j < 4; ++j) acc[i][j] = (f32x4)0.f;

    short8 rA[4], rW[4];
    auto LOADC = [&](int c) {
        const bool p1 = !CONCAT || (c < NCh);
        const long ko = p1 ? (long)c * 32 : (long)c * 32 - (K >> 1);
        #pragma unroll
        for (int j = 0; j < 4; ++j) {
            rA[j] = *(const short8*)((p1 ? aP1[j] : aP2[j]) + ko);
            if (!WLO || j < 2)               // j>=2 = W lo plane, dead under WLO
                rW[j] = *(const short8*)(wP[j] + (long)c * 32);
        }
    };
    auto STORE = [&](int c) {
        const int b = (c & 1) << 13;
        #pragma unroll
        for (int j = 0; j < 4; ++j) {
            *(short8*)(Asm + b + slda[j]) = rA[j];
            if (!WLO || j < 2)
                *(short8*)(Wsm + b + slda[j]) = rW[j];
        }
    };

    LOADC(0); STORE(0); LOADC(1);
    __syncthreads();

    for (int c = 0; c < NC; ++c) {
        const int b = (c & 1) << 13;
        short8 ah[4], al[4], wh[4], wl[4];
        #pragma unroll
        for (int f = 0; f < 4; ++f) {
            const short* ab = Asm + b + ((mq * 4 + f) * 64 + l) * 8;
            ah[f] = *(const short8*)ab;
            al[f] = *(const short8*)(ab + 4096);
            const short* wb = Wsm + b + ((nq * 4 + f) * 64 + l) * 8;
            wh[f] = *(const short8*)wb;
            if (!WLO) wl[f] = *(const short8*)(wb + 4096);
        }
        if (c + 1 < NC) STORE(c + 1);
        if (c + 2 < NC) LOADC(c + 2);
        #pragma unroll
        for (int mf = 0; mf < 4; ++mf)
            #pragma unroll
            for (int nf = 0; nf < 4; ++nf) {
                if constexpr (WLO) {
                    MF(al[mf], wh[nf], acc[mf][nf]);
                    MF(ah[mf], wh[nf], acc[mf][nf]);
                } else {
                    TRI(ah[mf], al[mf], wh[nf], wl[nf], acc[mf][nf]);
                }
            }
        __syncthreads();
    }

    #pragma unroll
    for (int mf = 0; mf < 4; ++mf) {
        #pragma unroll
        for (int reg = 0; reg < 4; ++reg) {
            const long R = Rbase + mq * 64 + mf * 16 + gl * 4 + reg;
            #pragma unroll
            for (int nf = 0; nf < 4; ++nf) {
                const int col = Cbase + nq * 64 + nf * 16 + r16;
                float v = acc[mf][nf][reg];
                if constexpr (MODE == 0) {
                    outf[R * (long)ldo + col] = v + bias[col];
                } else if constexpr (MODE == 1) {
                    if (bias) v += bias[col];
                    const unsigned short hi = f2bf(v), lo = f2bf(v - bf2f(hi));
                    outh[R * (long)ldo + col] = (short)hi;
                    outl[R * (long)ldo + col] = (short)lo;
                } else {
                    outf[R * (long)ldo + col] = tanhf(v);
                }
            }
        }
    }
}

// ============== recurrence GEMM core — K=1024, R11 staging/prefetch ==============
// MODE 0: gi-GEMM: TRI (W hi+lo), outf[R*H3 + p*HID + jc] = acc + bias.
// MODE 2: gate, gi given as bf16 hi/lo planes (stride H3).
// MODE 3: gate, gi given as f32 (stride H3).
template<int MODE>
__device__ __forceinline__ void gru_core(
    int bm, int bj,
    const short* __restrict__ Ah, const short* __restrict__ Al,
    const short* __restrict__ Wh,  const short* __restrict__ Wl,
    const float* __restrict__ bias,
    const float* __restrict__ gif,
    const short* __restrict__ gih, const short* __restrict__ gil,
    const float* __restrict__ hprev,
    float* __restrict__ outf,
    short* __restrict__ outh, short* __restrict__ outl)
{
    extern __shared__ short sm[];
    constexpr int P = 3;
    constexpr int NC = 16;                 // K = 1024
    constexpr bool WL = (MODE == 0);       // need W lo plane (TRI)
    const int ABUF = 8192, WBUF = P * 2048;
    short* Asm = sm;
    short* Wsm = sm + 2 * ABUF;
    const int tid = threadIdx.x;
    const int wv = tid >> 6, l = tid & 63;
    const int gl = l >> 4, r16 = l & 15;

    const short *ahP[2], *alP[2];
    int aLds[2];
    #pragma unroll
    for (int i = 0; i < 2; ++i) {
        const int s = tid + i * 256;
        const int row = ((s >> 6) & 3) * 16 + (s & 15);
        const int kg  = ((s >> 8) << 2) | ((s >> 4) & 3);
        const long r = (long)bm * 64 + row;
        ahP[i] = Ah + r * HID + kg * 8;
        alP[i] = Al + r * HID + kg * 8;
        aLds[i] = s * 8;
    }
    const bool doW = tid < P * 64;
    const short *whP[2], *wlP[2];
    int wLds[2] = {0, 0};
    if (doW) {
        #pragma unroll
        for (int i = 0; i < 2; ++i) {
            const int s = tid + i * P * 64;
            const int kcw = s / (P * 64);
            const int rem = s - kcw * (P * 64);
            const int p = rem >> 6, ll = rem & 63;
            const int jr = ll & 15, g = ll >> 4;
            const int kg = kcw * 4 + g;
            const long grow = (long)(p << 10) + bj * 16 + jr;
            whP[i] = Wh + grow * (long)HID + kg * 8;
            wlP[i] = WL ? Wl + grow * (long)HID + kg * 8 : whP[i];
            wLds[i] = s * 8;
        }
    }

    f32x4 acc[P];
    #pragma unroll
    for (int i = 0; i < P; ++i) acc[i] = (f32x4)0.f;

    short8 rAh[2], rAl[2], rWh[2], rWl[2];
    auto LOADC = [&](int c) {
        const long ko = (long)c * 64;
        #pragma unroll
        for (int i = 0; i < 2; ++i) {
            rAh[i] = *(const short8*)(ahP[i] + ko);
            rAl[i] = *(const short8*)(alP[i] + ko);
        }
        if (doW) {
            #pragma unroll
            for (int i = 0; i < 2; ++i) {
                rWh[i] = *(const short8*)(whP[i] + ko);
                if (WL) rWl[i] = *(const short8*)(wlP[i] + ko);
            }
        }
    };
    auto STORE = [&](int c) {
        const int b = c & 1;
        #pragma unroll
        for (int i = 0; i < 2; ++i) {
            *(short8*)(Asm + b * ABUF + aLds[i]) = rAh[i];
            *(short8*)(Asm + b * ABUF + 4096 + aLds[i]) = rAl[i];
        }
        if (doW) {
            #pragma unroll
            for (int i = 0; i < 2; ++i) {
                *(short8*)(Wsm + b * WBUF + wLds[i]) = rWh[i];
                if (WL) *(short8*)(Wsm + b * WBUF + P * 1024 + wLds[i]) = rWl[i];
            }
        }
    };

    LOADC(0); STORE(0); LOADC(1);
    __syncthreads();

    for (int c = 0; c < NC; ++c) {
        const int b = c & 1;
        short8 fah[2], fal[2], fwh[2][P], fwl[2][P];
        #pragma unroll
        for (int kc = 0; kc < 2; ++kc) {
            const short* ab = Asm + b * ABUF + (kc * 256 + wv * 64 + l) * 8;
            fah[kc] = *(const short8*)ab;
            fal[kc] = *(const short8*)(ab + 4096);
            #pragma unroll
            for (int p = 0; p < P; ++p) {
                const short* wb = Wsm + b * WBUF + (kc * (P * 64) + p * 64 + l) * 8;
                fwh[kc][p] = *(const short8*)wb;
                if (WL) fwl[kc][p] = *(const short8*)(wb + P * 1024);
            }
        }
        if (c + 1 < NC) STORE(c + 1);
        if (c + 2 < NC) LOADC(c + 2);
        #pragma unroll
        for (int kc = 0; kc < 2; ++kc) {
            #pragma unroll
            for (int p = 0; p < P; ++p) {
                if constexpr (MODE == 0) {
                    TRI(fah[kc], fal[kc], fwh[kc][p], fwl[kc][p], acc[p]);
                } else {
                    MF(fal[kc], fwh[kc][p], acc[p]);
                    MF(fah[kc], fwh[kc][p], acc[p]);
                }
            }
        }
        __syncthreads();
    }

    const int jc = bj * 16 + r16;
    #pragma unroll
    for (int reg = 0; reg < 4; ++reg) {
        const long R = (long)bm * 64 + wv * 16 + gl * 4 + reg;
        if constexpr (MODE == 0) {
            #pragma unroll
            for (int p = 0; p < P; ++p)
                outf[R * H3 + p * HID + jc] = acc[p][reg] + bias[p * HID + jc];
        } else {
            float gr, gz, gn;
            if constexpr (MODE == 2) {
                const size_t gR = (size_t)R * H3;
                gr = bf2f((unsigned short)gih[gR + jc]) + bf2f((unsigned short)gil[gR + jc]);
                gz = bf2f((unsigned short)gih[gR + HID + jc]) + bf2f((unsigned short)gil[gR + HID + jc]);
                gn = bf2f((unsigned short)gih[gR + 2 * HID + jc]) + bf2f((unsigned short)gil[gR + 2 * HID + jc]);
            } else {
                const float* orow = gif + R * H3;
                gr = orow[jc]; gz = orow[HID + jc]; gn = orow[2 * HID + jc];
            }
            const float rr = sigf(gr + acc[0][reg] + bias[jc]);
            const float zz = sigf(gz + acc[1][reg] + bias[HID + jc]);
            const float nn = tanhf(gn + rr * (acc[2][reg] + bias[2 * HID + jc]));
            const float h = (1.f - zz) * nn + zz * hprev[R * HID + jc];
            outf[R * HID + jc] = h;
            const unsigned short hb = f2bf(h), lb = f2bf(h - bf2f(hb));
            outh[R * HID + jc] = (short)hb;
            outl[R * HID + jc] = (short)lb;
        }
    }
}

// ============== 3-role pipelined step kernel (384 blocks, XCD-pinned) ==============
struct StepP {
    const short* hih; const short* hil;
    const float* h_in;
    const short* gi0h; const short* gi0l; float* gi1;
    const short* whh0h;
    const short* wih1h; const short* wih1l; const short* whh1h;
    const float* b_hh0; const float* b_ih1; const float* b_hh1;
    float* h0f; float* h1f;
    short* h0ah; short* h0al; short* h1ah; short* h1al;
};

__global__ __launch_bounds__(256) void step_k(int ph, StepP P)
{
    const int id = blockIdx.x;
    const int xcd = id & 7, sub = (id >> 3) & 7, top = id >> 6;
    const int role = top >> 1, bm = top & 1;
    const int bj = xcd * 8 + sub;

    if (role == 0) {
        const int t = ph;
        if (t >= T_STEPS) return;
        const short* a1h = t ? P.h0ah + (size_t)(t - 1) * BH : P.hih;
        const short* a1l = t ? P.h0al + (size_t)(t - 1) * BH : P.hil;
        gru_core<2>(bm, bj, a1h, a1l, P.whh0h, nullptr, P.b_hh0,
                    nullptr,
                    P.gi0h + (size_t)t * BATCH * H3,
                    P.gi0l + (size_t)t * BATCH * H3,
                    t ? P.h0f + (size_t)((t - 1) & 1) * BH : P.h_in,
                    P.h0f + (size_t)(t & 1) * BH,
                    P.h0ah + (size_t)t * BH, P.h0al + (size_t)t * BH);
    } else if (role == 1) {
        const int s = ph - 1;
        if (s < 0 || s >= T_STEPS) return;
        gru_core<0>(bm, bj,
                    P.h0ah + (size_t)s * BH, P.h0al + (size_t)s * BH,
                    P.wih1h, P.wih1l, P.b_ih1,
                    nullptr, nullptr, nullptr, nullptr,
                    P.gi1 + (size_t)(s & 1) * BATCH * H3,
                    nullptr, nullptr);
    } else {
        const int s = ph - 2;
        if (s < 0 || s >= T_STEPS) return;
        const short* a1h = s ? P.h1ah + (size_t)(s - 1) * BH : P.hih + BH;
        const short* a1l = s ? P.h1al + (size_t)(s - 1) * BH : P.hil + BH;
        gru_core<3>(bm, bj, a1h, a1l, P.whh1h, nullptr, P.b_hh1,
                    P.gi1 + (size_t)(s & 1) * BATCH * H3, nullptr, nullptr,
                    s ? P.h1f + (size_t)((s - 1) & 1) * BH : P.h_in + BH,
                    P.h1f + (size_t)(s & 1) * BH,
                    P.h1ah + (size_t)s * BH, P.h1al + (size_t)s * BH);
    }
}

// ============== batched attention scores + softmax (per b) ==============
__global__ __launch_bounds__(256) void scores_k(
    const short* __restrict__ Qh, const short* __restrict__ Ql,
    const short* __restrict__ Hh, const short* __restrict__ Hl,
    float* __restrict__ Pall)
{
    extern __shared__ short sm[];
    short* Asm = sm;
    short* Wsm = sm + 8192;
    const int b = blockIdx.x, tid = threadIdx.x;
    const int wv = tid >> 6, l = tid & 63;
    const int gl = l >> 4, cc = l & 15;

    const int arow = ((tid >> 6) & 3) * 16 + (tid & 15);
    const int ag   = (tid >> 4) & 3;
    const short* qhp = Qh + ((long)arow * BATCH + b) * HID + ag * 8;
    const short* qlp = Ql + ((long)arow * BATCH + b) * HID + ag * 8;
    const int aLds = tid * 8;

    const short *whp[2], *wlp[2]; int wLds[2];
    #pragma unroll
    for (int i = 0; i < 2; ++i) {
        const int s = tid + i * 256;
        const int srow = ((s >> 6) & 7) * 16 + (s & 15);
        const int sg   = (s >> 4) & 3;
        whp[i] = Hh + ((long)srow * BATCH + b) * HID + sg * 8;
        wlp[i] = Hl + ((long)srow * BATCH + b) * HID + sg * 8;
        wLds[i] = s * 8;
    }

    f32x4 acc[8];
    #pragma unroll
    for (int i = 0; i < 8; ++i) acc[i] = (f32x4)0.f;

    short8 rAh, rAl, rWh[2], rWl[2];
    auto LOADC = [&](int c) {
        rAh = *(const short8*)(qhp + c * 32);
        rAl = *(const short8*)(qlp + c * 32);
        #pragma unroll
        for (int i = 0; i < 2; ++i) {
            rWh[i] = *(const short8*)(whp[i] + c * 32);
            rWl[i] = *(const short8*)(wlp[i] + c * 32);
        }
    };
    auto STORE = [&](int c) {
        const int bb = c & 1;
        *(short8*)(Asm + bb * 4096 + aLds) = rAh;
        *(short8*)(Asm + bb * 4096 + 2048 + aLds) = rAl;
        #pragma unroll
        for (int i = 0; i < 2; ++i) {
            *(short8*)(Wsm + bb * 8192 + wLds[i]) = rWh[i];
            *(short8*)(Wsm + bb * 8192 + 4096 + wLds[i]) = rWl[i];
        }
    };

    LOADC(0); STORE(0); LOADC(1);
    __syncthreads();
    for (int c = 0; c < 32; ++c) {
        const int bb = c & 1;
        const short* abp = Asm + bb * 4096 + (wv * 64 + l) * 8;
        short8 ah = *(const short8*)abp;
        short8 al = *(const short8*)(abp + 2048);
        if (c + 1 < 32) STORE(c + 1);
        if (c + 2 < 32) LOADC(c + 2);
        #pragma unroll
        for (int jt = 0; jt < 8; ++jt) {
            const short* wbp = Wsm + bb * 8192 + (jt * 64 + l) * 8;
            short8 wh = *(const short8*)wbp;
            short8 wl = *(const short8*)(wbp + 4096);
            TRI(ah, al, wh, wl, acc[jt]);
        }
        __syncthreads();
    }

    #pragma unroll
    for (int reg = 0; reg < 4; ++reg) {
        float m = acc[0][reg];
        #pragma unroll
        for (int jt = 1; jt < 8; ++jt) m = fmaxf(m, acc[jt][reg]);
        #pragma unroll
        for (int off = 1; off < 16; off <<= 1) m = fmaxf(m, __shfl_xor(m, off));
        float e[8], ssum = 0.f;
        #pragma unroll
        for (int jt = 0; jt < 8; ++jt) { e[jt] = __expf(acc[jt][reg] - m); ssum += e[jt]; }
        #pragma unroll
        for (int off = 1; off < 16; off <<= 1) ssum += __shfl_xor(ssum, off);
        const float inv = 1.f / ssum;
        const int t = wv * 16 + gl * 4 + reg;
        #pragma unroll
        for (int jt = 0; jt < 8; ++jt)
            Pall[((long)t * BATCH + b) * SLEN + jt * 16 + cc] = e[jt] * inv;
    }
}

__global__ __launch_bounds__(256) void ctx_k(
    const float* __restrict__ Pall, const float* __restrict__ H,
    short* __restrict__ Ch, short* __restrict__ Cl)
{
    __shared__ float Ps[T_STEPS * SLEN];
    const int b = blockIdx.x, ht = blockIdx.y, tid = threadIdx.x;
    for (int i = 0; i < 32; ++i) {
        const int idx = i * 256 + tid;
        const int t = idx >> 7, s = idx & 127;
        Ps[idx] = Pall[((long)t * BATCH + b) * SLEN + s];
    }
    __syncthreads();
    const int col = ht * 256 + tid;
    for (int tg = 0; tg < 4; ++tg) {
        float a[16];
        #pragma unroll
        for (int j = 0; j < 16; ++j) a[j] = 0.f;
        for (int s = 0; s < SLEN; ++s) {
            const float hv = H[((long)s * BATCH + b) * HID + col];
            #pragma unroll
            for (int j = 0; j < 16; ++j)
                a[j] = fmaf(Ps[(tg * 16 + j) * SLEN + s], hv, a[j]);
        }
        #pragma unroll
        for (int j = 0; j < 16; ++j) {
            const long row = (long)(tg * 16 + j) * BATCH + b;
            const unsigned short hi = f2bf(a[j]);
            const unsigned short lo = f2bf(a[j] - bf2f(hi));
            Ch[row * HID + col] = (short)hi;
            Cl[row * HID + col] = (short)lo;
        }
    }
}

// =========================== launch ===========================
extern "C" void kernel_launch(void* const* d_in, const int* in_sizes, int n_in,
                              void* d_out, int out_size, void* d_ws, size_t ws_size,
                              hipStream_t stream)
{
    const int*   input = (const int*)  d_in[0];
    const float* h_in  = (const float*)d_in[1];
    const float* Hbuf  = (const float*)d_in[2];
    const float* emb   = (const float*)d_in[3];
    const float* w_ih  = (const float*)d_in[4];
    const float* w_hh  = (const float*)d_in[5];
    const float* b_ih  = (const float*)d_in[6];
    const float* b_hh  = (const float*)d_in[7];
    const float* L1    = (const float*)d_in[8];
    const float* L2    = (const float*)d_in[9];

    float* out = (float*)d_out;

    char* basep = (char*)d_ws;
    size_t off = 0;
    auto alloc = [&](size_t bytes) -> char* {
        off = (off + 255) & ~(size_t)255;
        char* p = basep + off; off += bytes; return p;
    };
    short* wih0h = (short*)alloc(3072L*1024*2); short* wih0l = (short*)alloc(3072L*1024*2);
    short* whh0h = (short*)alloc(3072L*1024*2);
    short* wih1h = (short*)alloc(3072L*1024*2); short* wih1l = (short*)alloc(3072L*1024*2);
    short* whh1h = (short*)alloc(3072L*1024*2);
    short* l1h   = (short*)alloc(1024L*1024*2); short* l1l   = (short*)alloc(1024L*1024*2);
    short* l2h   = (short*)alloc(1024L*2048*2); short* l2l   = (short*)alloc(1024L*2048*2);
    short* Hh    = (short*)alloc(16777216L*2);  short* Hl    = (short*)alloc(16777216L*2);
    short* hih   = (short*)alloc(262144L*2);    short* hil   = (short*)alloc(262144L*2);
    short* h0ah  = (short*)alloc(8388608L*2);   short* h0al  = (short*)alloc(8388608L*2);
    short* h1ah  = (short*)alloc(8388608L*2);   short* h1al  = (short*)alloc(8388608L*2);
    short* eqh   = (short*)alloc(8388608L*2);   short* eql   = (short*)alloc(8388608L*2);
    short* gi0h  = (short*)alloc(25165824L*2);  short* gi0l  = (short*)alloc(25165824L*2);
    float* gi1   = (float*)alloc(2L*BATCH*H3*4);
    float* h0f   = (float*)alloc(524288L*4);
    float* h1f   = (float*)alloc(524288L*4);
    float* Pall  = (float*)alloc(1048576L*4);
    short* ctxh  = gi0h;                        // gi0 planes dead after step loop
    short* ctxl  = gi0h + 8388608L;

    const dim3 blk(256);
    const size_t SMB = 32768 * sizeof(short);                      // 65536
    const size_t SM3 = (2 * 8192 + 2 * 3 * 2048) * sizeof(short);  // 57344

    // ---- phase 0: plane conversions ----
    conv_planes_k<true ><<<1536, blk, 0, stream>>>(w_ih, wih0h, wih0l);
    conv_planes_k<false><<<1536, blk, 0, stream>>>(w_hh, whh0h, nullptr);
    conv_planes_k<true ><<<1536, blk, 0, stream>>>(w_ih + 3145728L, wih1h, wih1l);
    conv_planes_k<false><<<1536, blk, 0, stream>>>(w_hh + 3145728L, whh1h, nullptr);
    conv_planes_k<true ><<<512,  blk, 0, stream>>>(L1, l1h, l1l);
    conv_planes_k<true ><<<1024, blk, 0, stream>>>(L2, l2h, l2l);
    conv_planes_k<true ><<<8192, blk, 0, stream>>>(Hbuf, Hh, Hl);
    conv_planes_k<true ><<<128,  blk, 0, stream>>>(h_in, hih, hil);
    conv_gather_k<<<4096, blk, 0, stream>>>(emb, input, eqh, eql);

    // gi0_all = E @ w_ih0^T + b_ih0 -> bf16 hi/lo planes (8192 x 3072), WLO
    gemm_big<1, false, true><<<dim3(1536), blk, SMB, stream>>>(
        eqh, eql, nullptr, nullptr, wih0h, wih0l, 1024, 24,
        b_ih, nullptr, gi0h, gi0l, H3);

    // ---- 3-role pipelined recurrence: 66 XCD-pinned launches ----
    StepP sp;
    sp.hih = hih; sp.hil = hil; sp.h_in = h_in;
    sp.gi0h = gi0h; sp.gi0l = gi0l; sp.gi1 = gi1;
    sp.whh0h = whh0h;
    sp.wih1h = wih1h; sp.wih1l = wih1l; sp.whh1h = whh1h;
    sp.b_hh0 = b_hh; sp.b_ih1 = b_ih + H3; sp.b_hh1 = b_hh + H3;
    sp.h0f = h0f; sp.h1f = h1f;
    sp.h0ah = h0ah; sp.h0al = h0al; sp.h1ah = h1ah; sp.h1al = h1al;
    for (int ph = 0; ph <= T_STEPS + 1; ++ph)
        step_k<<<dim3(384), blk, SM3, stream>>>(ph, sp);

    // ---- batched attention + output ----
    gemm_big<1, false, false><<<dim3(512), blk, SMB, stream>>>(
        h1ah, h1al, nullptr, nullptr, l1h, l1l, 1024, 8,
        nullptr, nullptr, eqh, eql, HID);
    scores_k<<<dim3(BATCH), blk, 49152, stream>>>(eqh, eql, Hh, Hl, Pall);
    ctx_k<<<dim3(BATCH, 4), blk, 0, stream>>>(Pall, Hbuf, ctxh, ctxl);
    gemm_big<2, true, false><<<dim3(512), blk, SMB, stream>>>(
        ctxh, ctxl, h1ah, h1al, l2h, l2l, 2048, 8,
        nullptr, out, nullptr, nullptr, HID);

    hipMemcpyAsync(out + (long)T_STEPS * BH, h0f + BH, (size_t)BH * 4,
                   hipMemcpyDeviceToDevice, stream);
    hipMemcpyAsync(out + (long)T_STEPS * BH + BH, h1f + BH, (size_t)BH * 4,
                   hipMemcpyDeviceToDevice, stream);
}

// Round 16
// 1996.581 us; speedup vs baseline: 2.8855x; 1.0458x over previous
//
#include <hip/hip_runtime.h>

#define T_STEPS 64
#define BATCH   128
#define HID     1024
#define H3      3072
#define EMBD    1024
#define SLEN    128
#define BH      (BATCH * HID)

typedef __attribute__((ext_vector_type(8))) short short8;
typedef __attribute__((ext_vector_type(4))) float f32x4;

__device__ __forceinline__ unsigned short f2bf(float x) {
    unsigned int u = __float_as_uint(x);
    unsigned int r = (u + 0x7fffu + ((u >> 16) & 1u)) >> 16;
    return (unsigned short)r;
}
__device__ __forceinline__ float bf2f(unsigned short h) {
    return __uint_as_float(((unsigned int)h) << 16);
}
__device__ __forceinline__ unsigned int pk(unsigned short a, unsigned short b) {
    return (unsigned int)a | ((unsigned int)b << 16);
}
__device__ __forceinline__ void cvt8(const float4& x, const float4& y,
                                     uint4& H, uint4& L) {
    unsigned short h0 = f2bf(x.x), h1 = f2bf(x.y), h2 = f2bf(x.z), h3 = f2bf(x.w);
    unsigned short h4 = f2bf(y.x), h5 = f2bf(y.y), h6 = f2bf(y.z), h7 = f2bf(y.w);
    unsigned short l0 = f2bf(x.x - bf2f(h0)), l1 = f2bf(x.y - bf2f(h1));
    unsigned short l2 = f2bf(x.z - bf2f(h2)), l3 = f2bf(x.w - bf2f(h3));
    unsigned short l4 = f2bf(y.x - bf2f(h4)), l5 = f2bf(y.y - bf2f(h5));
    unsigned short l6 = f2bf(y.z - bf2f(h6)), l7 = f2bf(y.w - bf2f(h7));
    H = make_uint4(pk(h0,h1), pk(h2,h3), pk(h4,h5), pk(h6,h7));
    L = make_uint4(pk(l0,l1), pk(l2,l3), pk(l4,l5), pk(l6,l7));
}
__device__ __forceinline__ float sigf(float x) {
    return 1.f / (1.f + __expf(-x));
}

#define MF(A, B, ACC) ACC = __builtin_amdgcn_mfma_f32_16x16x32_bf16(A, B, ACC, 0, 0, 0)
#define TRI(AH, AL, WH, WL, ACC)  MF(AH, WL, ACC); MF(AL, WH, ACC); MF(AH, WH, ACC);

// ============== plane-conversion kernels (run once per call) ==============
template<bool LO>
__global__ __launch_bounds__(256) void conv_planes_k(
    const float* __restrict__ src, short* __restrict__ hi, short* __restrict__ lo)
{
    const long i8 = (long)blockIdx.x * 256 + threadIdx.x;
    float4 x = ((const float4*)src)[i8 * 2];
    float4 y = ((const float4*)src)[i8 * 2 + 1];
    uint4 H, L; cvt8(x, y, H, L);
    ((uint4*)hi)[i8] = H;
    if (LO) ((uint4*)lo)[i8] = L;
}

__global__ __launch_bounds__(256) void conv_gather_k(
    const float* __restrict__ emb, const int* __restrict__ input,
    short* __restrict__ hi, short* __restrict__ lo)
{
    const long i8 = (long)blockIdx.x * 256 + threadIdx.x;
    const int c8 = (int)(i8 & 127);
    const long row = i8 >> 7;
    const float* s = emb + (size_t)input[row] * 1024 + c8 * 8;
    float4 x = ((const float4*)s)[0];
    float4 y = ((const float4*)s)[1];
    uint4 H, L; cvt8(x, y, H, L);
    ((uint4*)hi)[i8] = H; ((uint4*)lo)[i8] = L;
}

// ============== big batched GEMM: 128x128 block tile ==============
// MODE 1: plane store (+bias if given)   MODE 2: outf = tanh(acc)
template<int MODE, bool CONCAT, bool WLO>
__global__ __launch_bounds__(256, 2) void gemm_big(
    const short* __restrict__ A1h, const short* __restrict__ A1l,
    const short* __restrict__ A2h, const short* __restrict__ A2l,
    const short* __restrict__ Wh,  const short* __restrict__ Wl,
    int K, int nn,
    const float* __restrict__ bias,
    float* __restrict__ outf, short* __restrict__ outh, short* __restrict__ outl,
    int ldo)
{
    extern __shared__ short sm[];
    short* Asm = sm;
    short* Wsm = sm + 16384;
    const int tid = threadIdx.x;
    const int wv = tid >> 6, l = tid & 63;
    const int mq = wv >> 1, nq = wv & 1;
    const int gl = l >> 4, r16 = l & 15;

    const int cpx = gridDim.x >> 3;
    const int id = blockIdx.x;
    const int swz = (id & 7) * cpx + (id >> 3);
    const int bm = swz / nn, bn = swz % nn;
    const long Rbase = (long)bm * 128;
    const int  Cbase = bn * 128;

    const int lda = CONCAT ? (K >> 1) : K;
    const int NC = K >> 5;
    const int NCh = NC >> 1;

    const short *aP1[4], *aP2[4], *wP[4];
    int slda[4];
    #pragma unroll
    for (int j = 0; j < 4; ++j) {
        const int s = tid + j * 256;
        const int pl = s >> 9, sp = s & 511;
        const int row = ((sp >> 6) << 4) | (sp & 15);
        const int kg = (sp >> 4) & 3;
        slda[j] = s * 8;
        const short* a1 = pl ? A1l : A1h;
        aP1[j] = a1 + (Rbase + row) * (long)lda + kg * 8;
        if (CONCAT) {
            const short* a2 = pl ? A2l : A2h;
            aP2[j] = a2 + (Rbase + row) * (long)lda + kg * 8;
        } else aP2[j] = aP1[j];
        const short* wp = pl ? Wl : Wh;
        wP[j] = wp + ((long)Cbase + row) * (long)K + kg * 8;
    }

    f32x4 acc[4][4];
    #pragma unroll
    for (int i = 0; i < 4; ++i)
        #pragma unroll
        for (int j = 0; j < 4; ++j) acc[i][j] = (f32x4)0.f;

    short8 rA[4], rW[4];
    auto LOADC = [&](int c) {
        const bool p1 = !CONCAT || (c < NCh);
        const long ko = p1 ? (long)c * 32 : (long)c * 32 - (K >> 1);
        #pragma unroll
        for (int j = 0; j < 4; ++j) {
            rA[j] = *(const short8*)((p1 ? aP1[j] : aP2[j]) + ko);
            if (!WLO || j < 2)
                rW[j] = *(const short8*)(wP[j] + (long)c * 32);
        }
    };
    auto STORE = [&](int c) {
        const int b = (c & 1) << 13;
        #pragma unroll
        for (int j = 0; j < 4; ++j) {
            *(short8*)(Asm + b + slda[j]) = rA[j];
            if (!WLO || j < 2)
                *(short8*)(Wsm + b + slda[j]) = rW[j];
        }
    };

    LOADC(0); STORE(0); LOADC(1);
    __syncthreads();

    for (int c = 0; c < NC; ++c) {
        const int b = (c & 1) << 13;
        short8 ah[4], al[4], wh[4], wl[4];
        #pragma unroll
        for (int f = 0; f < 4; ++f) {
            const short* ab = Asm + b + ((mq * 4 + f) * 64 + l) * 8;
            ah[f] = *(const short8*)ab;
            al[f] = *(const short8*)(ab + 4096);
            const short* wb = Wsm + b + ((nq * 4 + f) * 64 + l) * 8;
            wh[f] = *(const short8*)wb;
            if (!WLO) wl[f] = *(const short8*)(wb + 4096);
        }
        if (c + 1 < NC) STORE(c + 1);
        if (c + 2 < NC) LOADC(c + 2);
        #pragma unroll
        for (int mf = 0; mf < 4; ++mf)
            #pragma unroll
            for (int nf = 0; nf < 4; ++nf) {
                if constexpr (WLO) {
                    MF(al[mf], wh[nf], acc[mf][nf]);
                    MF(ah[mf], wh[nf], acc[mf][nf]);
                } else {
                    TRI(ah[mf], al[mf], wh[nf], wl[nf], acc[mf][nf]);
                }
            }
        __syncthreads();
    }

    #pragma unroll
    for (int mf = 0; mf < 4; ++mf) {
        #pragma unroll
        for (int reg = 0; reg < 4; ++reg) {
            const long R = Rbase + mq * 64 + mf * 16 + gl * 4 + reg;
            #pragma unroll
            for (int nf = 0; nf < 4; ++nf) {
                const int col = Cbase + nq * 64 + nf * 16 + r16;
                float v = acc[mf][nf][reg];
                if constexpr (MODE == 1) {
                    if (bias) v += bias[col];
                    const unsigned short hi = f2bf(v), lo = f2bf(v - bf2f(hi));
                    outh[R * (long)ldo + col] = (short)hi;
                    outl[R * (long)ldo + col] = (short)lo;
                } else {
                    outf[R * (long)ldo + col] = tanhf(v);
                }
            }
        }
    }
}

// ============== recurrence GEMM core — K=1024, R11 staging/prefetch ==============
// MODE 0: gi-GEMM TRI (W hi+lo) -> f32 stride-H3 out (+bias).
// MODE 1: gi-GEMM DUO (W hi)    -> f32 stride-H3 out (+bias).
// MODE 3: gate DUO; gif = i-side f32 (stride H3); writes h f32 + planes.
template<int MODE>
__device__ __forceinline__ void gru_core(
    int bm, int bj,
    const short* __restrict__ Ah, const short* __restrict__ Al,
    const short* __restrict__ Wh,  const short* __restrict__ Wl,
    const float* __restrict__ bias,
    const float* __restrict__ gif,
    const float* __restrict__ hprev,
    float* __restrict__ outf,
    short* __restrict__ outh, short* __restrict__ outl)
{
    extern __shared__ short sm[];
    constexpr int P = 3;
    constexpr int NC = 16;                 // K = 1024
    constexpr bool WL = (MODE == 0);       // need W lo plane (TRI)
    const int ABUF = 8192, WBUF = P * 2048;
    short* Asm = sm;
    short* Wsm = sm + 2 * ABUF;
    const int tid = threadIdx.x;
    const int wv = tid >> 6, l = tid & 63;
    const int gl = l >> 4, r16 = l & 15;

    const short *ahP[2], *alP[2];
    int aLds[2];
    #pragma unroll
    for (int i = 0; i < 2; ++i) {
        const int s = tid + i * 256;
        const int row = ((s >> 6) & 3) * 16 + (s & 15);
        const int kg  = ((s >> 8) << 2) | ((s >> 4) & 3);
        const long r = (long)bm * 64 + row;
        ahP[i] = Ah + r * HID + kg * 8;
        alP[i] = Al + r * HID + kg * 8;
        aLds[i] = s * 8;
    }
    const bool doW = tid < P * 64;
    const short *whP[2], *wlP[2];
    int wLds[2] = {0, 0};
    if (doW) {
        #pragma unroll
        for (int i = 0; i < 2; ++i) {
            const int s = tid + i * P * 64;
            const int kcw = s / (P * 64);
            const int rem = s - kcw * (P * 64);
            const int p = rem >> 6, ll = rem & 63;
            const int jr = ll & 15, g = ll >> 4;
            const int kg = kcw * 4 + g;
            const long grow = (long)(p << 10) + bj * 16 + jr;
            whP[i] = Wh + grow * (long)HID + kg * 8;
            wlP[i] = WL ? Wl + grow * (long)HID + kg * 8 : whP[i];
            wLds[i] = s * 8;
        }
    }

    f32x4 acc[P];
    #pragma unroll
    for (int i = 0; i < P; ++i) acc[i] = (f32x4)0.f;

    short8 rAh[2], rAl[2], rWh[2], rWl[2];
    auto LOADC = [&](int c) {
        const long ko = (long)c * 64;
        #pragma unroll
        for (int i = 0; i < 2; ++i) {
            rAh[i] = *(const short8*)(ahP[i] + ko);
            rAl[i] = *(const short8*)(alP[i] + ko);
        }
        if (doW) {
            #pragma unroll
            for (int i = 0; i < 2; ++i) {
                rWh[i] = *(const short8*)(whP[i] + ko);
                if (WL) rWl[i] = *(const short8*)(wlP[i] + ko);
            }
        }
    };
    auto STORE = [&](int c) {
        const int b = c & 1;
        #pragma unroll
        for (int i = 0; i < 2; ++i) {
            *(short8*)(Asm + b * ABUF + aLds[i]) = rAh[i];
            *(short8*)(Asm + b * ABUF + 4096 + aLds[i]) = rAl[i];
        }
        if (doW) {
            #pragma unroll
            for (int i = 0; i < 2; ++i) {
                *(short8*)(Wsm + b * WBUF + wLds[i]) = rWh[i];
                if (WL) *(short8*)(Wsm + b * WBUF + P * 1024 + wLds[i]) = rWl[i];
            }
        }
    };

    LOADC(0); STORE(0); LOADC(1);
    __syncthreads();

    for (int c = 0; c < NC; ++c) {
        const int b = c & 1;
        short8 fah[2], fal[2], fwh[2][P], fwl[2][P];
        #pragma unroll
        for (int kc = 0; kc < 2; ++kc) {
            const short* ab = Asm + b * ABUF + (kc * 256 + wv * 64 + l) * 8;
            fah[kc] = *(const short8*)ab;
            fal[kc] = *(const short8*)(ab + 4096);
            #pragma unroll
            for (int p = 0; p < P; ++p) {
                const short* wb = Wsm + b * WBUF + (kc * (P * 64) + p * 64 + l) * 8;
                fwh[kc][p] = *(const short8*)wb;
                if (WL) fwl[kc][p] = *(const short8*)(wb + P * 1024);
            }
        }
        if (c + 1 < NC) STORE(c + 1);
        if (c + 2 < NC) LOADC(c + 2);
        #pragma unroll
        for (int kc = 0; kc < 2; ++kc) {
            #pragma unroll
            for (int p = 0; p < P; ++p) {
                if constexpr (MODE == 0) {
                    TRI(fah[kc], fal[kc], fwh[kc][p], fwl[kc][p], acc[p]);
                } else {
                    MF(fal[kc], fwh[kc][p], acc[p]);
                    MF(fah[kc], fwh[kc][p], acc[p]);
                }
            }
        }
        __syncthreads();
    }

    const int jc = bj * 16 + r16;
    #pragma unroll
    for (int reg = 0; reg < 4; ++reg) {
        const long R = (long)bm * 64 + wv * 16 + gl * 4 + reg;
        if constexpr (MODE != 3) {
            #pragma unroll
            for (int p = 0; p < P; ++p)
                outf[R * H3 + p * HID + jc] = acc[p][reg] + bias[p * HID + jc];
        } else {
            const float* orow = gif + R * H3;
            const float rr = sigf(orow[jc] + acc[0][reg] + bias[jc]);
            const float zz = sigf(orow[HID + jc] + acc[1][reg] + bias[HID + jc]);
            const float nn = tanhf(orow[2 * HID + jc] + rr * (acc[2][reg] + bias[2 * HID + jc]));
            const float h = (1.f - zz) * nn + zz * hprev[R * HID + jc];
            outf[R * HID + jc] = h;
            const unsigned short hb = f2bf(h), lb = f2bf(h - bf2f(hb));
            outh[R * HID + jc] = (short)hb;
            outl[R * HID + jc] = (short)lb;
        }
    }
}

// ============== 4-role pipelined step kernel (512 blocks, XCD-pinned) ==============
// id -> xcd=id&7, sub=(id>>3)&7, top=id>>6 (0..7): role=top>>1, bm=top&1,
// bj=xcd*8+sub. Phase ph: role0 -> h0_ph ; role1 -> gi1_{ph-1} ;
// role2 -> h1_{ph-2} ; role3 -> gi0_{ph+2} (look-ahead, DUO wih0h).
struct StepP {
    const short* hih; const short* hil;
    const float* h_in;
    const short* eqh; const short* eql;
    float* gi0; float* gi1;
    const short* whh0h; const short* wih0h;
    const short* wih1h; const short* wih1l; const short* whh1h;
    const float* b_ih0; const float* b_hh0; const float* b_ih1; const float* b_hh1;
    float* h0f; float* h1f;
    short* h0ah; short* h0al; short* h1ah; short* h1al;
};

__global__ __launch_bounds__(256) void step_k(int ph, StepP P)
{
    const int id = blockIdx.x;
    const int xcd = id & 7, sub = (id >> 3) & 7, top = id >> 6;
    const int role = top >> 1, bm = top & 1;
    const int bj = xcd * 8 + sub;

    if (role == 0) {
        const int t = ph;
        if (t >= T_STEPS) return;
        const short* a1h = t ? P.h0ah + (size_t)(t - 1) * BH : P.hih;
        const short* a1l = t ? P.h0al + (size_t)(t - 1) * BH : P.hil;
        gru_core<3>(bm, bj, a1h, a1l, P.whh0h, nullptr, P.b_hh0,
                    P.gi0 + (size_t)t * BATCH * H3,
                    t ? P.h0f + (size_t)((t - 1) & 1) * BH : P.h_in,
                    P.h0f + (size_t)(t & 1) * BH,
                    P.h0ah + (size_t)t * BH, P.h0al + (size_t)t * BH);
    } else if (role == 1) {
        const int s = ph - 1;
        if (s < 0 || s >= T_STEPS) return;
        gru_core<0>(bm, bj,
                    P.h0ah + (size_t)s * BH, P.h0al + (size_t)s * BH,
                    P.wih1h, P.wih1l, P.b_ih1,
                    nullptr, nullptr,
                    P.gi1 + (size_t)(s & 1) * BATCH * H3,
                    nullptr, nullptr);
    } else if (role == 2) {
        const int s = ph - 2;
        if (s < 0 || s >= T_STEPS) return;
        const short* a1h = s ? P.h1ah + (size_t)(s - 1) * BH : P.hih + BH;
        const short* a1l = s ? P.h1al + (size_t)(s - 1) * BH : P.hil + BH;
        gru_core<3>(bm, bj, a1h, a1l, P.whh1h, nullptr, P.b_hh1,
                    P.gi1 + (size_t)(s & 1) * BATCH * H3,
                    s ? P.h1f + (size_t)((s - 1) & 1) * BH : P.h_in + BH,
                    P.h1f + (size_t)(s & 1) * BH,
                    P.h1ah + (size_t)s * BH, P.h1al + (size_t)s * BH);
    } else {
        const int u = ph + 2;
        if (u >= T_STEPS) return;
        gru_core<1>(bm, bj,
                    P.eqh + (size_t)u * BH, P.eql + (size_t)u * BH,
                    P.wih0h, nullptr, P.b_ih0,
                    nullptr, nullptr,
                    P.gi0 + (size_t)u * BATCH * H3,
                    nullptr, nullptr);
    }
}

// prologue: gi0 for steps 0..1 (256 blocks: t=id>>7, bm=(id>>6)&1, bj=id&63)
__global__ __launch_bounds__(256) void step_pre_k(StepP P)
{
    const int id = blockIdx.x;
    const int t = id >> 7, bm = (id >> 6) & 1, bj = id & 63;
    gru_core<1>(bm, bj,
                P.eqh + (size_t)t * BH, P.eql + (size_t)t * BH,
                P.wih0h, nullptr, P.b_ih0,
                nullptr, nullptr,
                P.gi0 + (size_t)t * BATCH * H3,
                nullptr, nullptr);
}

// ============== batched attention scores + softmax (per b) ==============
__global__ __launch_bounds__(256) void scores_k(
    const short* __restrict__ Qh, const short* __restrict__ Ql,
    const short* __restrict__ Hh, const short* __restrict__ Hl,
    float* __restrict__ Pall)
{
    extern __shared__ short sm[];
    short* Asm = sm;
    short* Wsm = sm + 8192;
    const int b = blockIdx.x, tid = threadIdx.x;
    const int wv = tid >> 6, l = tid & 63;
    const int gl = l >> 4, cc = l & 15;

    const int arow = ((tid >> 6) & 3) * 16 + (tid & 15);
    const int ag   = (tid >> 4) & 3;
    const short* qhp = Qh + ((long)arow * BATCH + b) * HID + ag * 8;
    const short* qlp = Ql + ((long)arow * BATCH + b) * HID + ag * 8;
    const int aLds = tid * 8;

    const short *whp[2], *wlp[2]; int wLds[2];
    #pragma unroll
    for (int i = 0; i < 2; ++i) {
        const int s = tid + i * 256;
        const int srow = ((s >> 6) & 7) * 16 + (s & 15);
        const int sg   = (s >> 4) & 3;
        whp[i] = Hh + ((long)srow * BATCH + b) * HID + sg * 8;
        wlp[i] = Hl + ((long)srow * BATCH + b) * HID + sg * 8;
        wLds[i] = s * 8;
    }

    f32x4 acc[8];
    #pragma unroll
    for (int i = 0; i < 8; ++i) acc[i] = (f32x4)0.f;

    short8 rAh, rAl, rWh[2], rWl[2];
    auto LOADC = [&](int c) {
        rAh = *(const short8*)(qhp + c * 32);
        rAl = *(const short8*)(qlp + c * 32);
        #pragma unroll
        for (int i = 0; i < 2; ++i) {
            rWh[i] = *(const short8*)(whp[i] + c * 32);
            rWl[i] = *(const short8*)(wlp[i] + c * 32);
        }
    };
    auto STORE = [&](int c) {
        const int bb = c & 1;
        *(short8*)(Asm + bb * 4096 + aLds) = rAh;
        *(short8*)(Asm + bb * 4096 + 2048 + aLds) = rAl;
        #pragma unroll
        for (int i = 0; i < 2; ++i) {
            *(short8*)(Wsm + bb * 8192 + wLds[i]) = rWh[i];
            *(short8*)(Wsm + bb * 8192 + 4096 + wLds[i]) = rWl[i];
        }
    };

    LOADC(0); STORE(0); LOADC(1);
    __syncthreads();
    for (int c = 0; c < 32; ++c) {
        const int bb = c & 1;
        const short* abp = Asm + bb * 4096 + (wv * 64 + l) * 8;
        short8 ah = *(const short8*)abp;
        short8 al = *(const short8*)(abp + 2048);
        if (c + 1 < 32) STORE(c + 1);
        if (c + 2 < 32) LOADC(c + 2);
        #pragma unroll
        for (int jt = 0; jt < 8; ++jt) {
            const short* wbp = Wsm + bb * 8192 + (jt * 64 + l) * 8;
            short8 wh = *(const short8*)wbp;
            short8 wl = *(const short8*)(wbp + 4096);
            TRI(ah, al, wh, wl, acc[jt]);
        }
        __syncthreads();
    }

    #pragma unroll
    for (int reg = 0; reg < 4; ++reg) {
        float m = acc[0][reg];
        #pragma unroll
        for (int jt = 1; jt < 8; ++jt) m = fmaxf(m, acc[jt][reg]);
        #pragma unroll
        for (int off = 1; off < 16; off <<= 1) m = fmaxf(m, __shfl_xor(m, off));
        float e[8], ssum = 0.f;
        #pragma unroll
        for (int jt = 0; jt < 8; ++jt) { e[jt] = __expf(acc[jt][reg] - m); ssum += e[jt]; }
        #pragma unroll
        for (int off = 1; off < 16; off <<= 1) ssum += __shfl_xor(ssum, off);
        const float inv = 1.f / ssum;
        const int t = wv * 16 + gl * 4 + reg;
        #pragma unroll
        for (int jt = 0; jt < 8; ++jt)
            Pall[((long)t * BATCH + b) * SLEN + jt * 16 + cc] = e[jt] * inv;
    }
}

__global__ __launch_bounds__(256) void ctx_k(
    const float* __restrict__ Pall, const float* __restrict__ H,
    short* __restrict__ Ch, short* __restrict__ Cl)
{
    __shared__ float Ps[T_STEPS * SLEN];
    const int b = blockIdx.x, ht = blockIdx.y, tid = threadIdx.x;
    for (int i = 0; i < 32; ++i) {
        const int idx = i * 256 + tid;
        const int t = idx >> 7, s = idx & 127;
        Ps[idx] = Pall[((long)t * BATCH + b) * SLEN + s];
    }
    __syncthreads();
    const int col = ht * 256 + tid;
    for (int tg = 0; tg < 4; ++tg) {
        float a[16];
        #pragma unroll
        for (int j = 0; j < 16; ++j) a[j] = 0.f;
        for (int s = 0; s < SLEN; ++s) {
            const float hv = H[((long)s * BATCH + b) * HID + col];
            #pragma unroll
            for (int j = 0; j < 16; ++j)
                a[j] = fmaf(Ps[(tg * 16 + j) * SLEN + s], hv, a[j]);
        }
        #pragma unroll
        for (int j = 0; j < 16; ++j) {
            const long row = (long)(tg * 16 + j) * BATCH + b;
            const unsigned short hi = f2bf(a[j]);
            const unsigned short lo = f2bf(a[j] - bf2f(hi));
            Ch[row * HID + col] = (short)hi;
            Cl[row * HID + col] = (short)lo;
        }
    }
}

// =========================== launch ===========================
extern "C" void kernel_launch(void* const* d_in, const int* in_sizes, int n_in,
                              void* d_out, int out_size, void* d_ws, size_t ws_size,
                              hipStream_t stream)
{
    const int*   input = (const int*)  d_in[0];
    const float* h_in  = (const float*)d_in[1];
    const float* Hbuf  = (const float*)d_in[2];
    const float* emb   = (const float*)d_in[3];
    const float* w_ih  = (const float*)d_in[4];
    const float* w_hh  = (const float*)d_in[5];
    const float* b_ih  = (const float*)d_in[6];
    const float* b_hh  = (const float*)d_in[7];
    const float* L1    = (const float*)d_in[8];
    const float* L2    = (const float*)d_in[9];

    float* out = (float*)d_out;

    char* basep = (char*)d_ws;
    size_t off = 0;
    auto alloc = [&](size_t bytes) -> char* {
        off = (off + 255) & ~(size_t)255;
        char* p = basep + off; off += bytes; return p;
    };
    short* wih0h = (short*)alloc(3072L*1024*2);
    short* whh0h = (short*)alloc(3072L*1024*2);
    short* wih1h = (short*)alloc(3072L*1024*2); short* wih1l = (short*)alloc(3072L*1024*2);
    short* whh1h = (short*)alloc(3072L*1024*2);
    short* l1h   = (short*)alloc(1024L*1024*2); short* l1l   = (short*)alloc(1024L*1024*2);
    short* l2h   = (short*)alloc(1024L*2048*2); short* l2l   = (short*)alloc(1024L*2048*2);
    short* Hh    = (short*)alloc(16777216L*2);  short* Hl    = (short*)alloc(16777216L*2);
    short* hih   = (short*)alloc(262144L*2);    short* hil   = (short*)alloc(262144L*2);
    short* h0ah  = (short*)alloc(8388608L*2);   short* h0al  = (short*)alloc(8388608L*2);
    short* h1ah  = (short*)alloc(8388608L*2);   short* h1al  = (short*)alloc(8388608L*2);
    short* eqh   = (short*)alloc(8388608L*2);   short* eql   = (short*)alloc(8388608L*2);
    float* gi0   = (float*)alloc(25165824L*4);
    float* gi1   = (float*)alloc(2L*BATCH*H3*4);
    float* h0f   = (float*)alloc(524288L*4);
    float* h1f   = (float*)alloc(524288L*4);
    float* Pall  = (float*)alloc(1048576L*4);
    short* ctxh  = (short*)gi0;                 // gi0 dead after step loop
    short* ctxl  = ctxh + 8388608L;

    const dim3 blk(256);
    const size_t SMB = 32768 * sizeof(short);                      // 65536
    const size_t SM3 = (2 * 8192 + 2 * 3 * 2048) * sizeof(short);  // 57344

    // ---- phase 0: plane conversions ----
    conv_planes_k<false><<<1536, blk, 0, stream>>>(w_ih, wih0h, nullptr);
    conv_planes_k<false><<<1536, blk, 0, stream>>>(w_hh, whh0h, nullptr);
    conv_planes_k<true ><<<1536, blk, 0, stream>>>(w_ih + 3145728L, wih1h, wih1l);
    conv_planes_k<false><<<1536, blk, 0, stream>>>(w_hh + 3145728L, whh1h, nullptr);
    conv_planes_k<true ><<<512,  blk, 0, stream>>>(L1, l1h, l1l);
    conv_planes_k<true ><<<1024, blk, 0, stream>>>(L2, l2h, l2l);
    conv_planes_k<true ><<<8192, blk, 0, stream>>>(Hbuf, Hh, Hl);
    conv_planes_k<true ><<<128,  blk, 0, stream>>>(h_in, hih, hil);
    conv_gather_k<<<4096, blk, 0, stream>>>(emb, input, eqh, eql);

    // ---- 4-role pipelined recurrence ----
    StepP sp;
    sp.hih = hih; sp.hil = hil; sp.h_in = h_in;
    sp.eqh = eqh; sp.eql = eql;
    sp.gi0 = gi0; sp.gi1 = gi1;
    sp.whh0h = whh0h; sp.wih0h = wih0h;
    sp.wih1h = wih1h; sp.wih1l = wih1l; sp.whh1h = whh1h;
    sp.b_ih0 = b_ih; sp.b_hh0 = b_hh;
    sp.b_ih1 = b_ih + H3; sp.b_hh1 = b_hh + H3;
    sp.h0f = h0f; sp.h1f = h1f;
    sp.h0ah = h0ah; sp.h0al = h0al; sp.h1ah = h1ah; sp.h1al = h1al;

    step_pre_k<<<dim3(256), blk, SM3, stream>>>(sp);    // gi0[0..1]
    for (int ph = 0; ph <= T_STEPS + 1; ++ph)
        step_k<<<dim3(512), blk, SM3, stream>>>(ph, sp);

    // ---- batched attention + output ----
    gemm_big<1, false, false><<<dim3(512), blk, SMB, stream>>>(
        h1ah, h1al, nullptr, nullptr, l1h, l1l, 1024, 8,
        nullptr, nullptr, eqh, eql, HID);
    scores_k<<<dim3(BATCH), blk, 49152, stream>>>(eqh, eql, Hh, Hl, Pall);
    ctx_k<<<dim3(BATCH, 4), blk, 0, stream>>>(Pall, Hbuf, ctxh, ctxl);
    gemm_big<2, true, false><<<dim3(512), blk, SMB, stream>>>(
        ctxh, ctxl, h1ah, h1al, l2h, l2l, 2048, 8,
        nullptr, out, nullptr, nullptr, HID);

    hipMemcpyAsync(out + (long)T_STEPS * BH, h0f + BH, (size_t)BH * 4,
                   hipMemcpyDeviceToDevice, stream);
    hipMemcpyAsync(out + (long)T_STEPS * BH + BH, h1f + BH, (size_t)BH * 4,
                   hipMemcpyDeviceToDevice, stream);
}

// Round 17
// 1988.158 us; speedup vs baseline: 2.8977x; 1.0042x over previous
//
#include <hip/hip_runtime.h>

#define T_STEPS 64
#define BATCH   128
#define HID     1024
#define H3      3072
#define EMBD    1024
#define SLEN    128
#define BH      (BATCH * HID)

typedef __attribute__((ext_vector_type(8))) short short8;
typedef __attribute__((ext_vector_type(4))) float f32x4;

__device__ __forceinline__ unsigned short f2bf(float x) {
    unsigned int u = __float_as_uint(x);
    unsigned int r = (u + 0x7fffu + ((u >> 16) & 1u)) >> 16;
    return (unsigned short)r;
}
__device__ __forceinline__ float bf2f(unsigned short h) {
    return __uint_as_float(((unsigned int)h) << 16);
}
__device__ __forceinline__ unsigned int pk(unsigned short a, unsigned short b) {
    return (unsigned int)a | ((unsigned int)b << 16);
}
__device__ __forceinline__ void cvt8(const float4& x, const float4& y,
                                     uint4& H, uint4& L) {
    unsigned short h0 = f2bf(x.x), h1 = f2bf(x.y), h2 = f2bf(x.z), h3 = f2bf(x.w);
    unsigned short h4 = f2bf(y.x), h5 = f2bf(y.y), h6 = f2bf(y.z), h7 = f2bf(y.w);
    unsigned short l0 = f2bf(x.x - bf2f(h0)), l1 = f2bf(x.y - bf2f(h1));
    unsigned short l2 = f2bf(x.z - bf2f(h2)), l3 = f2bf(x.w - bf2f(h3));
    unsigned short l4 = f2bf(y.x - bf2f(h4)), l5 = f2bf(y.y - bf2f(h5));
    unsigned short l6 = f2bf(y.z - bf2f(h6)), l7 = f2bf(y.w - bf2f(h7));
    H = make_uint4(pk(h0,h1), pk(h2,h3), pk(h4,h5), pk(h6,h7));
    L = make_uint4(pk(l0,l1), pk(l2,l3), pk(l4,l5), pk(l6,l7));
}
__device__ __forceinline__ float sigf(float x) {
    return 1.f / (1.f + __expf(-x));
}

#define MF(A, B, ACC) ACC = __builtin_amdgcn_mfma_f32_16x16x32_bf16(A, B, ACC, 0, 0, 0)
#define TRI(AH, AL, WH, WL, ACC)  MF(AH, WL, ACC); MF(AL, WH, ACC); MF(AH, WH, ACC);

// ============== plane-conversion kernels (run once per call) ==============
template<bool LO>
__global__ __launch_bounds__(256) void conv_planes_k(
    const float* __restrict__ src, short* __restrict__ hi, short* __restrict__ lo)
{
    const long i8 = (long)blockIdx.x * 256 + threadIdx.x;
    float4 x = ((const float4*)src)[i8 * 2];
    float4 y = ((const float4*)src)[i8 * 2 + 1];
    uint4 H, L; cvt8(x, y, H, L);
    ((uint4*)hi)[i8] = H;
    if (LO) ((uint4*)lo)[i8] = L;
}

// 3 hi-only weight conversions fused (3 x 1536 blocks)
__global__ __launch_bounds__(256) void conv_w3_k(
    const float* __restrict__ s0, short* __restrict__ d0,
    const float* __restrict__ s1, short* __restrict__ d1,
    const float* __restrict__ s2, short* __restrict__ d2)
{
    const int id = blockIdx.x;
    const float* s; short* d; int sub;
    if (id < 1536)       { s = s0; d = d0; sub = id; }
    else if (id < 3072)  { s = s1; d = d1; sub = id - 1536; }
    else                 { s = s2; d = d2; sub = id - 3072; }
    const long i8 = (long)sub * 256 + threadIdx.x;
    float4 x = ((const float4*)s)[i8 * 2];
    float4 y = ((const float4*)s)[i8 * 2 + 1];
    uint4 H, L; cvt8(x, y, H, L);
    ((uint4*)d)[i8] = H;
    (void)L;
}

// L1 (512 blocks) + L2 (1024 blocks) hi/lo fused
__global__ __launch_bounds__(256) void conv_l12_k(
    const float* __restrict__ s0, short* __restrict__ h0p, short* __restrict__ l0p,
    const float* __restrict__ s1, short* __restrict__ h1p, short* __restrict__ l1p)
{
    const int id = blockIdx.x;
    const float* s; short* hh; short* ll; int sub;
    if (id < 512) { s = s0; hh = h0p; ll = l0p; sub = id; }
    else          { s = s1; hh = h1p; ll = l1p; sub = id - 512; }
    const long i8 = (long)sub * 256 + threadIdx.x;
    float4 x = ((const float4*)s)[i8 * 2];
    float4 y = ((const float4*)s)[i8 * 2 + 1];
    uint4 H, L; cvt8(x, y, H, L);
    ((uint4*)hh)[i8] = H;
    ((uint4*)ll)[i8] = L;
}

__global__ __launch_bounds__(256) void conv_gather_k(
    const float* __restrict__ emb, const int* __restrict__ input,
    short* __restrict__ hi, short* __restrict__ lo)
{
    const long i8 = (long)blockIdx.x * 256 + threadIdx.x;
    const int c8 = (int)(i8 & 127);
    const long row = i8 >> 7;
    const float* s = emb + (size_t)input[row] * 1024 + c8 * 8;
    float4 x = ((const float4*)s)[0];
    float4 y = ((const float4*)s)[1];
    uint4 H, L; cvt8(x, y, H, L);
    ((uint4*)hi)[i8] = H; ((uint4*)lo)[i8] = L;
}

// ============== big batched GEMM: 128x128 block tile ==============
// MODE 1: plane store (+bias if given)   MODE 2: outf = tanh(acc)
template<int MODE, bool CONCAT, bool WLO>
__global__ __launch_bounds__(256, 2) void gemm_big(
    const short* __restrict__ A1h, const short* __restrict__ A1l,
    const short* __restrict__ A2h, const short* __restrict__ A2l,
    const short* __restrict__ Wh,  const short* __restrict__ Wl,
    int K, int nn,
    const float* __restrict__ bias,
    float* __restrict__ outf, short* __restrict__ outh, short* __restrict__ outl,
    int ldo)
{
    extern __shared__ short sm[];
    short* Asm = sm;
    short* Wsm = sm + 16384;
    const int tid = threadIdx.x;
    const int wv = tid >> 6, l = tid & 63;
    const int mq = wv >> 1, nq = wv & 1;
    const int gl = l >> 4, r16 = l & 15;

    const int cpx = gridDim.x >> 3;
    const int id = blockIdx.x;
    const int swz = (id & 7) * cpx + (id >> 3);
    const int bm = swz / nn, bn = swz % nn;
    const long Rbase = (long)bm * 128;
    const int  Cbase = bn * 128;

    const int lda = CONCAT ? (K >> 1) : K;
    const int NC = K >> 5;
    const int NCh = NC >> 1;

    const short *aP1[4], *aP2[4], *wP[4];
    int slda[4];
    #pragma unroll
    for (int j = 0; j < 4; ++j) {
        const int s = tid + j * 256;
        const int pl = s >> 9, sp = s & 511;
        const int row = ((sp >> 6) << 4) | (sp & 15);
        const int kg = (sp >> 4) & 3;
        slda[j] = s * 8;
        const short* a1 = pl ? A1l : A1h;
        aP1[j] = a1 + (Rbase + row) * (long)lda + kg * 8;
        if (CONCAT) {
            const short* a2 = pl ? A2l : A2h;
            aP2[j] = a2 + (Rbase + row) * (long)lda + kg * 8;
        } else aP2[j] = aP1[j];
        const short* wp = pl ? Wl : Wh;
        wP[j] = wp + ((long)Cbase + row) * (long)K + kg * 8;
    }

    f32x4 acc[4][4];
    #pragma unroll
    for (int i = 0; i < 4; ++i)
        #pragma unroll
        for (int j = 0; j < 4; ++j) acc[i][j] = (f32x4)0.f;

    short8 rA[4], rW[4];
    auto LOADC = [&](int c) {
        const bool p1 = !CONCAT || (c < NCh);
        const long ko = p1 ? (long)c * 32 : (long)c * 32 - (K >> 1);
        #pragma unroll
        for (int j = 0; j < 4; ++j) {
            rA[j] = *(const short8*)((p1 ? aP1[j] : aP2[j]) + ko);
            if (!WLO || j < 2)
                rW[j] = *(const short8*)(wP[j] + (long)c * 32);
        }
    };
    auto STORE = [&](int c) {
        const int b = (c & 1) << 13;
        #pragma unroll
        for (int j = 0; j < 4; ++j) {
            *(short8*)(Asm + b + slda[j]) = rA[j];
            if (!WLO || j < 2)
                *(short8*)(Wsm + b + slda[j]) = rW[j];
        }
    };

    LOADC(0); STORE(0); LOADC(1);
    __syncthreads();

    for (int c = 0; c < NC; ++c) {
        const int b = (c & 1) << 13;
        short8 ah[4], al[4], wh[4], wl[4];
        #pragma unroll
        for (int f = 0; f < 4; ++f) {
            const short* ab = Asm + b + ((mq * 4 + f) * 64 + l) * 8;
            ah[f] = *(const short8*)ab;
            al[f] = *(const short8*)(ab + 4096);
            const short* wb = Wsm + b + ((nq * 4 + f) * 64 + l) * 8;
            wh[f] = *(const short8*)wb;
            if (!WLO) wl[f] = *(const short8*)(wb + 4096);
        }
        if (c + 1 < NC) STORE(c + 1);
        if (c + 2 < NC) LOADC(c + 2);
        #pragma unroll
        for (int mf = 0; mf < 4; ++mf)
            #pragma unroll
            for (int nf = 0; nf < 4; ++nf) {
                if constexpr (WLO) {
                    MF(al[mf], wh[nf], acc[mf][nf]);
                    MF(ah[mf], wh[nf], acc[mf][nf]);
                } else {
                    TRI(ah[mf], al[mf], wh[nf], wl[nf], acc[mf][nf]);
                }
            }
        __syncthreads();
    }

    #pragma unroll
    for (int mf = 0; mf < 4; ++mf) {
        #pragma unroll
        for (int reg = 0; reg < 4; ++reg) {
            const long R = Rbase + mq * 64 + mf * 16 + gl * 4 + reg;
            #pragma unroll
            for (int nf = 0; nf < 4; ++nf) {
                const int col = Cbase + nq * 64 + nf * 16 + r16;
                float v = acc[mf][nf][reg];
                if constexpr (MODE == 1) {
                    if (bias) v += bias[col];
                    const unsigned short hi = f2bf(v), lo = f2bf(v - bf2f(hi));
                    outh[R * (long)ldo + col] = (short)hi;
                    outl[R * (long)ldo + col] = (short)lo;
                } else {
                    outf[R * (long)ldo + col] = tanhf(v);
                }
            }
        }
    }
}

// ============== recurrence GEMM core — K=1024, R11 staging/prefetch ==============
// MODE 0: gi-GEMM TRI (W hi+lo) -> f32 stride-H3 out (+bias).
// MODE 1: gi-GEMM DUO (W hi)    -> f32 stride-H3 out (+bias).
// MODE 3: gate DUO; gif = i-side f32 (stride H3); writes h f32 + planes
//         (+ optional second f32 copy to outf2 for the final step).
template<int MODE>
__device__ __forceinline__ void gru_core(
    int bm, int bj,
    const short* __restrict__ Ah, const short* __restrict__ Al,
    const short* __restrict__ Wh,  const short* __restrict__ Wl,
    const float* __restrict__ bias,
    const float* __restrict__ gif,
    const float* __restrict__ hprev,
    float* __restrict__ outf,
    short* __restrict__ outh, short* __restrict__ outl,
    float* __restrict__ outf2)
{
    extern __shared__ short sm[];
    constexpr int P = 3;
    constexpr int NC = 16;                 // K = 1024
    constexpr bool WL = (MODE == 0);       // need W lo plane (TRI)
    const int ABUF = 8192, WBUF = P * 2048;
    short* Asm = sm;
    short* Wsm = sm + 2 * ABUF;
    const int tid = threadIdx.x;
    const int wv = tid >> 6, l = tid & 63;
    const int gl = l >> 4, r16 = l & 15;

    const short *ahP[2], *alP[2];
    int aLds[2];
    #pragma unroll
    for (int i = 0; i < 2; ++i) {
        const int s = tid + i * 256;
        const int row = ((s >> 6) & 3) * 16 + (s & 15);
        const int kg  = ((s >> 8) << 2) | ((s >> 4) & 3);
        const long r = (long)bm * 64 + row;
        ahP[i] = Ah + r * HID + kg * 8;
        alP[i] = Al + r * HID + kg * 8;
        aLds[i] = s * 8;
    }
    const bool doW = tid < P * 64;
    const short *whP[2], *wlP[2];
    int wLds[2] = {0, 0};
    if (doW) {
        #pragma unroll
        for (int i = 0; i < 2; ++i) {
            const int s = tid + i * P * 64;
            const int kcw = s / (P * 64);
            const int rem = s - kcw * (P * 64);
            const int p = rem >> 6, ll = rem & 63;
            const int jr = ll & 15, g = ll >> 4;
            const int kg = kcw * 4 + g;
            const long grow = (long)(p << 10) + bj * 16 + jr;
            whP[i] = Wh + grow * (long)HID + kg * 8;
            wlP[i] = WL ? Wl + grow * (long)HID + kg * 8 : whP[i];
            wLds[i] = s * 8;
        }
    }

    f32x4 acc[P];
    #pragma unroll
    for (int i = 0; i < P; ++i) acc[i] = (f32x4)0.f;

    short8 rAh[2], rAl[2], rWh[2], rWl[2];
    auto LOADC = [&](int c) {
        const long ko = (long)c * 64;
        #pragma unroll
        for (int i = 0; i < 2; ++i) {
            rAh[i] = *(const short8*)(ahP[i] + ko);
            rAl[i] = *(const short8*)(alP[i] + ko);
        }
        if (doW) {
            #pragma unroll
            for (int i = 0; i < 2; ++i) {
                rWh[i] = *(const short8*)(whP[i] + ko);
                if (WL) rWl[i] = *(const short8*)(wlP[i] + ko);
            }
        }
    };
    auto STORE = [&](int c) {
        const int b = c & 1;
        #pragma unroll
        for (int i = 0; i < 2; ++i) {
            *(short8*)(Asm + b * ABUF + aLds[i]) = rAh[i];
            *(short8*)(Asm + b * ABUF + 4096 + aLds[i]) = rAl[i];
        }
        if (doW) {
            #pragma unroll
            for (int i = 0; i < 2; ++i) {
                *(short8*)(Wsm + b * WBUF + wLds[i]) = rWh[i];
                if (WL) *(short8*)(Wsm + b * WBUF + P * 1024 + wLds[i]) = rWl[i];
            }
        }
    };

    LOADC(0); STORE(0); LOADC(1);
    __syncthreads();

    for (int c = 0; c < NC; ++c) {
        const int b = c & 1;
        short8 fah[2], fal[2], fwh[2][P], fwl[2][P];
        #pragma unroll
        for (int kc = 0; kc < 2; ++kc) {
            const short* ab = Asm + b * ABUF + (kc * 256 + wv * 64 + l) * 8;
            fah[kc] = *(const short8*)ab;
            fal[kc] = *(const short8*)(ab + 4096);
            #pragma unroll
            for (int p = 0; p < P; ++p) {
                const short* wb = Wsm + b * WBUF + (kc * (P * 64) + p * 64 + l) * 8;
                fwh[kc][p] = *(const short8*)wb;
                if (WL) fwl[kc][p] = *(const short8*)(wb + P * 1024);
            }
        }
        if (c + 1 < NC) STORE(c + 1);
        if (c + 2 < NC) LOADC(c + 2);
        #pragma unroll
        for (int kc = 0; kc < 2; ++kc) {
            #pragma unroll
            for (int p = 0; p < P; ++p) {
                if constexpr (MODE == 0) {
                    TRI(fah[kc], fal[kc], fwh[kc][p], fwl[kc][p], acc[p]);
                } else {
                    MF(fal[kc], fwh[kc][p], acc[p]);
                    MF(fah[kc], fwh[kc][p], acc[p]);
                }
            }
        }
        __syncthreads();
    }

    const int jc = bj * 16 + r16;
    #pragma unroll
    for (int reg = 0; reg < 4; ++reg) {
        const long R = (long)bm * 64 + wv * 16 + gl * 4 + reg;
        if constexpr (MODE != 3) {
            #pragma unroll
            for (int p = 0; p < P; ++p)
                outf[R * H3 + p * HID + jc] = acc[p][reg] + bias[p * HID + jc];
        } else {
            const float* orow = gif + R * H3;
            const float rr = sigf(orow[jc] + acc[0][reg] + bias[jc]);
            const float zz = sigf(orow[HID + jc] + acc[1][reg] + bias[HID + jc]);
            const float nn = tanhf(orow[2 * HID + jc] + rr * (acc[2][reg] + bias[2 * HID + jc]));
            const float h = (1.f - zz) * nn + zz * hprev[R * HID + jc];
            outf[R * HID + jc] = h;
            if (outf2) outf2[R * HID + jc] = h;
            const unsigned short hb = f2bf(h), lb = f2bf(h - bf2f(hb));
            outh[R * HID + jc] = (short)hb;
            outl[R * HID + jc] = (short)lb;
        }
    }
}

// ============== 4-role pipelined step kernel (512 blocks, XCD-pinned) ==============
// Phase ph: role0 -> h0_ph ; role1 -> gi1_{ph-1} ; role2 -> h1_{ph-2} ;
// role3 -> gi0_{ph+2} (look-ahead, DUO wih0h).
struct StepP {
    const short* hih; const short* hil;
    const float* h_in;
    const short* eqh; const short* eql;
    float* gi0; float* gi1;
    const short* whh0h; const short* wih0h;
    const short* wih1h; const short* wih1l; const short* whh1h;
    const float* b_ih0; const float* b_hh0; const float* b_ih1; const float* b_hh1;
    float* h0f; float* h1f;
    short* h0ah; short* h0al; short* h1ah; short* h1al;
    float* hf0dst; float* hf1dst;     // d_out final-state tail
};

__global__ __launch_bounds__(256) void step_k(int ph, StepP P)
{
    const int id = blockIdx.x;
    const int xcd = id & 7, sub = (id >> 3) & 7, top = id >> 6;
    const int role = top >> 1, bm = top & 1;
    const int bj = xcd * 8 + sub;

    if (role == 0) {
        const int t = ph;
        if (t >= T_STEPS) return;
        const short* a1h = t ? P.h0ah + (size_t)(t - 1) * BH : P.hih;
        const short* a1l = t ? P.h0al + (size_t)(t - 1) * BH : P.hil;
        gru_core<3>(bm, bj, a1h, a1l, P.whh0h, nullptr, P.b_hh0,
                    P.gi0 + (size_t)t * BATCH * H3,
                    t ? P.h0f + (size_t)((t - 1) & 1) * BH : P.h_in,
                    P.h0f + (size_t)(t & 1) * BH,
                    P.h0ah + (size_t)t * BH, P.h0al + (size_t)t * BH,
                    (t == T_STEPS - 1) ? P.hf0dst : nullptr);
    } else if (role == 1) {
        const int s = ph - 1;
        if (s < 0 || s >= T_STEPS) return;
        gru_core<0>(bm, bj,
                    P.h0ah + (size_t)s * BH, P.h0al + (size_t)s * BH,
                    P.wih1h, P.wih1l, P.b_ih1,
                    nullptr, nullptr,
                    P.gi1 + (size_t)(s & 1) * BATCH * H3,
                    nullptr, nullptr, nullptr);
    } else if (role == 2) {
        const int s = ph - 2;
        if (s < 0 || s >= T_STEPS) return;
        const short* a1h = s ? P.h1ah + (size_t)(s - 1) * BH : P.hih + BH;
        const short* a1l = s ? P.h1al + (size_t)(s - 1) * BH : P.hil + BH;
        gru_core<3>(bm, bj, a1h, a1l, P.whh1h, nullptr, P.b_hh1,
                    P.gi1 + (size_t)(s & 1) * BATCH * H3,
                    s ? P.h1f + (size_t)((s - 1) & 1) * BH : P.h_in + BH,
                    P.h1f + (size_t)(s & 1) * BH,
                    P.h1ah + (size_t)s * BH, P.h1al + (size_t)s * BH,
                    (s == T_STEPS - 1) ? P.hf1dst : nullptr);
    } else {
        const int u = ph + 2;
        if (u >= T_STEPS) return;
        gru_core<1>(bm, bj,
                    P.eqh + (size_t)u * BH, P.eql + (size_t)u * BH,
                    P.wih0h, nullptr, P.b_ih0,
                    nullptr, nullptr,
                    P.gi0 + (size_t)u * BATCH * H3,
                    nullptr, nullptr, nullptr);
    }
}

// prologue: gi0 for steps 0..1 (256 blocks: t=id>>7, bm=(id>>6)&1, bj=id&63)
__global__ __launch_bounds__(256) void step_pre_k(StepP P)
{
    const int id = blockIdx.x;
    const int t = id >> 7, bm = (id >> 6) & 1, bj = id & 63;
    gru_core<1>(bm, bj,
                P.eqh + (size_t)t * BH, P.eql + (size_t)t * BH,
                P.wih0h, nullptr, P.b_ih0,
                nullptr, nullptr,
                P.gi0 + (size_t)t * BATCH * H3,
                nullptr, nullptr, nullptr);
}

// ============== batched attention scores + softmax (per b) ==============
__global__ __launch_bounds__(256) void scores_k(
    const short* __restrict__ Qh, const short* __restrict__ Ql,
    const short* __restrict__ Hh, const short* __restrict__ Hl,
    float* __restrict__ Pall)
{
    extern __shared__ short sm[];
    short* Asm = sm;
    short* Wsm = sm + 8192;
    const int b = blockIdx.x, tid = threadIdx.x;
    const int wv = tid >> 6, l = tid & 63;
    const int gl = l >> 4, cc = l & 15;

    const int arow = ((tid >> 6) & 3) * 16 + (tid & 15);
    const int ag   = (tid >> 4) & 3;
    const short* qhp = Qh + ((long)arow * BATCH + b) * HID + ag * 8;
    const short* qlp = Ql + ((long)arow * BATCH + b) * HID + ag * 8;
    const int aLds = tid * 8;

    const short *whp[2], *wlp[2]; int wLds[2];
    #pragma unroll
    for (int i = 0; i < 2; ++i) {
        const int s = tid + i * 256;
        const int srow = ((s >> 6) & 7) * 16 + (s & 15);
        const int sg   = (s >> 4) & 3;
        whp[i] = Hh + ((long)srow * BATCH + b) * HID + sg * 8;
        wlp[i] = Hl + ((long)srow * BATCH + b) * HID + sg * 8;
        wLds[i] = s * 8;
    }

    f32x4 acc[8];
    #pragma unroll
    for (int i = 0; i < 8; ++i) acc[i] = (f32x4)0.f;

    short8 rAh, rAl, rWh[2], rWl[2];
    auto LOADC = [&](int c) {
        rAh = *(const short8*)(qhp + c * 32);
        rAl = *(const short8*)(qlp + c * 32);
        #pragma unroll
        for (int i = 0; i < 2; ++i) {
            rWh[i] = *(const short8*)(whp[i] + c * 32);
            rWl[i] = *(const short8*)(wlp[i] + c * 32);
        }
    };
    auto STORE = [&](int c) {
        const int bb = c & 1;
        *(short8*)(Asm + bb * 4096 + aLds) = rAh;
        *(short8*)(Asm + bb * 4096 + 2048 + aLds) = rAl;
        #pragma unroll
        for (int i = 0; i < 2; ++i) {
            *(short8*)(Wsm + bb * 8192 + wLds[i]) = rWh[i];
            *(short8*)(Wsm + bb * 8192 + 4096 + wLds[i]) = rWl[i];
        }
    };

    LOADC(0); STORE(0); LOADC(1);
    __syncthreads();
    for (int c = 0; c < 32; ++c) {
        const int bb = c & 1;
        const short* abp = Asm + bb * 4096 + (wv * 64 + l) * 8;
        short8 ah = *(const short8*)abp;
        short8 al = *(const short8*)(abp + 2048);
        if (c + 1 < 32) STORE(c + 1);
        if (c + 2 < 32) LOADC(c + 2);
        #pragma unroll
        for (int jt = 0; jt < 8; ++jt) {
            const short* wbp = Wsm + bb * 8192 + (jt * 64 + l) * 8;
            short8 wh = *(const short8*)wbp;
            short8 wl = *(const short8*)(wbp + 4096);
            TRI(ah, al, wh, wl, acc[jt]);
        }
        __syncthreads();
    }

    #pragma unroll
    for (int reg = 0; reg < 4; ++reg) {
        float m = acc[0][reg];
        #pragma unroll
        for (int jt = 1; jt < 8; ++jt) m = fmaxf(m, acc[jt][reg]);
        #pragma unroll
        for (int off = 1; off < 16; off <<= 1) m = fmaxf(m, __shfl_xor(m, off));
        float e[8], ssum = 0.f;
        #pragma unroll
        for (int jt = 0; jt < 8; ++jt) { e[jt] = __expf(acc[jt][reg] - m); ssum += e[jt]; }
        #pragma unroll
        for (int off = 1; off < 16; off <<= 1) ssum += __shfl_xor(ssum, off);
        const float inv = 1.f / ssum;
        const int t = wv * 16 + gl * 4 + reg;
        #pragma unroll
        for (int jt = 0; jt < 8; ++jt)
            Pall[((long)t * BATCH + b) * SLEN + jt * 16 + cc] = e[jt] * inv;
    }
}

__global__ __launch_bounds__(256) void ctx_k(
    const float* __restrict__ Pall, const float* __restrict__ H,
    short* __restrict__ Ch, short* __restrict__ Cl)
{
    __shared__ float Ps[T_STEPS * SLEN];
    const int b = blockIdx.x, ht = blockIdx.y, tid = threadIdx.x;
    for (int i = 0; i < 32; ++i) {
        const int idx = i * 256 + tid;
        const int t = idx >> 7, s = idx & 127;
        Ps[idx] = Pall[((long)t * BATCH + b) * SLEN + s];
    }
    __syncthreads();
    const int col = ht * 256 + tid;
    for (int tg = 0; tg < 4; ++tg) {
        float a[16];
        #pragma unroll
        for (int j = 0; j < 16; ++j) a[j] = 0.f;
        for (int s = 0; s < SLEN; ++s) {
            const float hv = H[((long)s * BATCH + b) * HID + col];
            #pragma unroll
            for (int j = 0; j < 16; ++j)
                a[j] = fmaf(Ps[(tg * 16 + j) * SLEN + s], hv, a[j]);
        }
        #pragma unroll
        for (int j = 0; j < 16; ++j) {
            const long row = (long)(tg * 16 + j) * BATCH + b;
            const unsigned short hi = f2bf(a[j]);
            const unsigned short lo = f2bf(a[j] - bf2f(hi));
            Ch[row * HID + col] = (short)hi;
            Cl[row * HID + col] = (short)lo;
        }
    }
}

// =========================== launch ===========================
extern "C" void kernel_launch(void* const* d_in, const int* in_sizes, int n_in,
                              void* d_out, int out_size, void* d_ws, size_t ws_size,
                              hipStream_t stream)
{
    const int*   input = (const int*)  d_in[0];
    const float* h_in  = (const float*)d_in[1];
    const float* Hbuf  = (const float*)d_in[2];
    const float* emb   = (const float*)d_in[3];
    const float* w_ih  = (const float*)d_in[4];
    const float* w_hh  = (const float*)d_in[5];
    const float* b_ih  = (const float*)d_in[6];
    const float* b_hh  = (const float*)d_in[7];
    const float* L1    = (const float*)d_in[8];
    const float* L2    = (const float*)d_in[9];

    float* out = (float*)d_out;

    char* basep = (char*)d_ws;
    size_t off = 0;
    auto alloc = [&](size_t bytes) -> char* {
        off = (off + 255) & ~(size_t)255;
        char* p = basep + off; off += bytes; return p;
    };
    short* wih0h = (short*)alloc(3072L*1024*2);
    short* whh0h = (short*)alloc(3072L*1024*2);
    short* wih1h = (short*)alloc(3072L*1024*2); short* wih1l = (short*)alloc(3072L*1024*2);
    short* whh1h = (short*)alloc(3072L*1024*2);
    short* l1h   = (short*)alloc(1024L*1024*2); short* l1l   = (short*)alloc(1024L*1024*2);
    short* l2h   = (short*)alloc(1024L*2048*2); short* l2l   = (short*)alloc(1024L*2048*2);
    short* Hh    = (short*)alloc(16777216L*2);  short* Hl    = (short*)alloc(16777216L*2);
    short* hih   = (short*)alloc(262144L*2);    short* hil   = (short*)alloc(262144L*2);
    short* h0ah  = (short*)alloc(8388608L*2);   short* h0al  = (short*)alloc(8388608L*2);
    short* h1ah  = (short*)alloc(8388608L*2);   short* h1al  = (short*)alloc(8388608L*2);
    short* eqh   = (short*)alloc(8388608L*2);   short* eql   = (short*)alloc(8388608L*2);
    float* gi0   = (float*)alloc(25165824L*4);
    float* gi1   = (float*)alloc(2L*BATCH*H3*4);
    float* h0f   = (float*)alloc(524288L*4);
    float* h1f   = (float*)alloc(524288L*4);
    float* Pall  = (float*)alloc(1048576L*4);
    short* ctxh  = (short*)gi0;                 // gi0 dead after step loop
    short* ctxl  = ctxh + 8388608L;

    const dim3 blk(256);
    const size_t SMB = 32768 * sizeof(short);                      // 65536
    const size_t SM3 = (2 * 8192 + 2 * 3 * 2048) * sizeof(short);  // 57344

    // ---- phase 0: plane conversions (fused) ----
    conv_w3_k<<<4608, blk, 0, stream>>>(w_ih, wih0h,
                                        w_hh, whh0h,
                                        w_hh + 3145728L, whh1h);
    conv_planes_k<true ><<<1536, blk, 0, stream>>>(w_ih + 3145728L, wih1h, wih1l);
    conv_l12_k<<<1536, blk, 0, stream>>>(L1, l1h, l1l, L2, l2h, l2l);
    conv_planes_k<true ><<<8192, blk, 0, stream>>>(Hbuf, Hh, Hl);
    conv_planes_k<true ><<<128,  blk, 0, stream>>>(h_in, hih, hil);
    conv_gather_k<<<4096, blk, 0, stream>>>(emb, input, eqh, eql);

    // ---- 4-role pipelined recurrence ----
    StepP sp;
    sp.hih = hih; sp.hil = hil; sp.h_in = h_in;
    sp.eqh = eqh; sp.eql = eql;
    sp.gi0 = gi0; sp.gi1 = gi1;
    sp.whh0h = whh0h; sp.wih0h = wih0h;
    sp.wih1h = wih1h; sp.wih1l = wih1l; sp.whh1h = whh1h;
    sp.b_ih0 = b_ih; sp.b_hh0 = b_hh;
    sp.b_ih1 = b_ih + H3; sp.b_hh1 = b_hh + H3;
    sp.h0f = h0f; sp.h1f = h1f;
    sp.h0ah = h0ah; sp.h0al = h0al; sp.h1ah = h1ah; sp.h1al = h1al;
    sp.hf0dst = out + (long)T_STEPS * BH;
    sp.hf1dst = out + (long)T_STEPS * BH + BH;

    step_pre_k<<<dim3(256), blk, SM3, stream>>>(sp);    // gi0[0..1]
    for (int ph = 0; ph <= T_STEPS + 1; ++ph)
        step_k<<<dim3(512), blk, SM3, stream>>>(ph, sp);

    // ---- batched attention + output ----
    gemm_big<1, false, false><<<dim3(512), blk, SMB, stream>>>(
        h1ah, h1al, nullptr, nullptr, l1h, l1l, 1024, 8,
        nullptr, nullptr, eqh, eql, HID);
    scores_k<<<dim3(BATCH), blk, 49152, stream>>>(eqh, eql, Hh, Hl, Pall);
    ctx_k<<<dim3(BATCH, 4), blk, 0, stream>>>(Pall, Hbuf, ctxh, ctxl);
    gemm_big<2, true, false><<<dim3(512), blk, SMB, stream>>>(
        ctxh, ctxl, h1ah, h1al, l2h, l2l, 2048, 8,
        nullptr, out, nullptr, nullptr, HID);
}